// Round 8
// baseline (667.434 us; speedup 1.0000x reference)
//
#include <hip/hip_runtime.h>
#include <hip/hip_bf16.h>

// ---------------------------------------------------------------------------
// Wide&Deep forward: 5-layer GEMM chain (bf16 MFMA) + wide-sum + domain head.
// L1: gemm_sb<8,256> — 256x256 single-buffered (64KB LDS) -> 2 blocks/CU.
// L2: gemm_sb<4,128> — 256x128 single-buffered (48KB LDS) -> 2 blocks/CU.
//   Drain-per-tile hidden by sibling block (m97/m114 mechanism).
// L3/L4: gemm_128 (R6). L5: gemm_bt (m97). + converts + head.
// ---------------------------------------------------------------------------

typedef __attribute__((ext_vector_type(8))) short short8;
typedef __attribute__((ext_vector_type(4))) float f32x4;

static __device__ __forceinline__ unsigned short f2bf_bits(float x) {
  __hip_bfloat16 h = __float2bfloat16(x);
  return __builtin_bit_cast(unsigned short, h);
}
static __device__ __forceinline__ float bf_bits2f(unsigned short u) {
  __hip_bfloat16 h = __builtin_bit_cast(__hip_bfloat16, u);
  return __bfloat162float(h);
}

static __device__ __forceinline__ void gload16(const void* g, void* l) {
  __builtin_amdgcn_global_load_lds(
      (const __attribute__((address_space(1))) void*)g,
      (__attribute__((address_space(3))) void*)l, 16, 0, 0);
}

static __device__ __forceinline__ unsigned lds_u32(const void* p) {
  return (unsigned)(uintptr_t)(const __attribute__((address_space(3))) void*)p;
}

// compiler-invisible LDS read
static __device__ __forceinline__ short8 dsr(unsigned addr) {
  short8 r;
  asm volatile("ds_read_b128 %0, %1" : "=v"(r) : "v"(addr));
  return r;
}

#define MFMA16(a, b, c) __builtin_amdgcn_mfma_f32_16x16x32_bf16((a), (b), (c), 0, 0, 0)
#define SB0() __builtin_amdgcn_sched_barrier(0)
#define PRIO(x) __builtin_amdgcn_s_setprio(x)
#define BAR() __builtin_amdgcn_s_barrier()

// ---------------------------------------------------------------------------
// Transpose-convert: W [K][N] f32 -> Wt [N][K] bf16
// ---------------------------------------------------------------------------
__global__ void transpose_convert(const float* __restrict__ W,
                                  __hip_bfloat16* __restrict__ Wt,
                                  int K, int N) {
  __shared__ float tile[64][65];
  const int k0 = blockIdx.y * 64;
  const int n0 = blockIdx.x * 64;
  const int t  = threadIdx.x;
  const int tn = t & 63;
  const int t4 = t >> 6;
#pragma unroll
  for (int p = 0; p < 16; ++p) {
    int kl = p * 4 + t4;
    tile[kl][tn] = W[(size_t)(k0 + kl) * N + (n0 + tn)];
  }
  __syncthreads();
#pragma unroll
  for (int p = 0; p < 16; ++p) {
    int nl = p * 4 + t4;
    Wt[(size_t)(n0 + nl) * K + (k0 + tn)] = __float2bfloat16(tile[tn][nl]);
  }
}

// ---------------------------------------------------------------------------
// f32 -> bf16 bulk convert
// ---------------------------------------------------------------------------
__global__ void f32_to_bf16(const float* __restrict__ in,
                            unsigned short* __restrict__ out, int n8) {
  int i = blockIdx.x * blockDim.x + threadIdx.x;
  if (i >= n8) return;
  const f32x4* p = (const f32x4*)in + (size_t)i * 2;
  f32x4 a = p[0], b = p[1];
  short8 o;
  o[0] = (short)f2bf_bits(a[0]); o[1] = (short)f2bf_bits(a[1]);
  o[2] = (short)f2bf_bits(a[2]); o[3] = (short)f2bf_bits(a[3]);
  o[4] = (short)f2bf_bits(b[0]); o[5] = (short)f2bf_bits(b[1]);
  o[6] = (short)f2bf_bits(b[2]); o[7] = (short)f2bf_bits(b[3]);
  *(short8*)(out + (size_t)i * 8) = o;
}

// ---------------------------------------------------------------------------
// gemm_sb<MI,BN>: BM=256 x BN tile, BK=64, 8 waves (256/(MI*16) m-groups x
// BN/64 n-groups), SINGLE-buffered LDS (32KB A + BN*128 B) -> 2 blocks/CU.
// Loop: vmcnt(0); BAR [publish t]; rolling reads+MFMA; lgkm(0); BAR [all
// reads retired]; stage(t+1). Drain hidden by sibling block.
// ---------------------------------------------------------------------------
template <int MI, int BN>
__global__ __launch_bounds__(512, 4) void gemm_sb(
    const __hip_bfloat16* __restrict__ A,
    const __hip_bfloat16* __restrict__ Bt,
    const float* __restrict__ bias,
    __hip_bfloat16* __restrict__ Cb,
    float* __restrict__ Cf,
    int N, int K, int nbx) {
  constexpr int NWN = BN / 64;
  __shared__ char lds[32768 + BN * 128];

  const int tid  = threadIdx.x;
  const int lane = tid & 63;
  const int wid  = tid >> 6;
  const int wm   = wid / NWN;
  const int wn   = wid % NWN;

  // T1: bijective XCD swizzle (gridDim.x % 8 == 0)
  const int nwg = gridDim.x;
  const int cpx = nwg >> 3;
  const int id  = blockIdx.x;
  const int swz = (id & 7) * cpx + (id >> 3);
  const int bm  = (swz / nbx) * 256;
  const int bn  = (swz % nbx) * BN;

  const int ln15 = lane & 15;
  const unsigned cswz = (unsigned)((((lane >> 4) ^ (lane & 7)) << 4));
  const unsigned lbase = lds_u32(lds);
  const unsigned aoff = lbase + (unsigned)((wm * (MI * 16) + ln15) * 128) + cswz;
  const unsigned boff = lbase + 32768u + (unsigned)((wn * 64 + ln15) * 128) + cswz;

  const int nt = K >> 6;
  const int swc = (tid & 7) ^ ((tid >> 3) & 7);
  const __hip_bfloat16* baseA = A  + (size_t)(bm + (tid >> 3)) * K + swc * 8;
  const __hip_bfloat16* baseB = Bt + (size_t)(bn + (tid >> 3)) * K + swc * 8;
  const unsigned ldst0 = (unsigned)(tid * 16);

  auto stage = [&](int kt) {
#pragma unroll
    for (int q = 0; q < 4; ++q)
      gload16(baseA + (size_t)((q * 64) * K + kt * 64), lds + q * 8192 + ldst0);
#pragma unroll
    for (int q = 0; q < NWN; ++q)
      gload16(baseB + (size_t)((q * 64) * K + kt * 64),
              lds + 32768 + q * 8192 + ldst0);
  };

  f32x4 acc[MI][4] = {};

  stage(0);
  for (int t = 0; t < nt; ++t) {
    asm volatile("s_waitcnt vmcnt(0)");
    BAR();  // publish tile t (and prior-tile reads all retired before stage)

    // B fragments (8 reads) + first A pair
    short8 bv[4][2];
#pragma unroll
    for (int nj = 0; nj < 4; ++nj)
#pragma unroll
      for (int kk = 0; kk < 2; ++kk)
        bv[nj][kk] = dsr((boff + (unsigned)(nj * 2048)) ^ (unsigned)(kk << 6));
    short8 aC[2], aN[2];
    aC[0] = dsr(aoff);
    aC[1] = dsr(aoff ^ 64u);

#pragma unroll
    for (int mi = 0; mi < MI; ++mi) {
      if (mi + 1 < MI) {
        unsigned ad = aoff + (unsigned)((mi + 1) * 2048);
        aN[0] = dsr(ad);
        aN[1] = dsr(ad ^ 64u);
        asm volatile("s_waitcnt lgkmcnt(2)");  // bv + aC resident
      } else {
        asm volatile("s_waitcnt lgkmcnt(0)");
      }
      SB0();
      PRIO(1);
#pragma unroll
      for (int kk = 0; kk < 2; ++kk)
#pragma unroll
        for (int nj = 0; nj < 4; ++nj)
          acc[mi][nj] = MFMA16(aC[kk], bv[nj][kk], acc[mi][nj]);
      PRIO(0);
      aC[0] = aN[0];
      aC[1] = aN[1];
    }
    BAR();  // all waves' reads of tile t retired -> overwrite safe
    if (t + 1 < nt) stage(t + 1);
  }

  // epilogue: bias + relu; C/D: col = lane&15, row = (lane>>4)*4 + r
  float biasv[4];
#pragma unroll
  for (int nj = 0; nj < 4; ++nj)
    biasv[nj] = bias[bn + wn * 64 + nj * 16 + ln15];

#pragma unroll
  for (int mi = 0; mi < MI; ++mi) {
    int row0 = bm + wm * (MI * 16) + mi * 16 + (lane >> 4) * 4;
#pragma unroll
    for (int nj = 0; nj < 4; ++nj) {
      int col = bn + wn * 64 + nj * 16 + ln15;
#pragma unroll
      for (int r = 0; r < 4; ++r) {
        float v = acc[mi][nj][r] + biasv[nj];
        v = v > 0.f ? v : 0.f;
        size_t idx = (size_t)(row0 + r) * N + col;
        Cb[idx] = __float2bfloat16(v);
        if (Cf) Cf[idx] = v;
      }
    }
  }
}

// ---------------------------------------------------------------------------
// gemm_128: 128x256, BK=64, 8 waves 2x4 (wave tile 64x64), R6 2-barrier
// double-buffered schedule. Loads/tile = 6; publish vmcnt(2); prologue vmcnt(3).
// ---------------------------------------------------------------------------
__global__ __launch_bounds__(512, 2) void gemm_128(
    const __hip_bfloat16* __restrict__ A,
    const __hip_bfloat16* __restrict__ Bt,
    const float* __restrict__ bias,
    __hip_bfloat16* __restrict__ Cb,
    float* __restrict__ Cf,
    int N, int K, int nbx) {
  __shared__ char lds[98304];

  const int tid  = threadIdx.x;
  const int lane = tid & 63;
  const int wid  = tid >> 6;
  const int wm   = wid >> 2;
  const int wn   = wid & 3;

  const int nwg = gridDim.x;
  const int cpx = nwg >> 3;
  const int id  = blockIdx.x;
  const int swz = (id & 7) * cpx + (id >> 3);
  const int bm  = (swz / nbx) * 128;
  const int bn  = (swz % nbx) * 256;

  const int ln15 = lane & 15;
  const unsigned cswz = (unsigned)((((lane >> 4) ^ (lane & 7)) << 4));

  const unsigned lbase = lds_u32(lds);
  const unsigned arow0 = lbase + (unsigned)(wm * 64 + ln15) * 128u + cswz;
  const unsigned brow0 = lbase + 16384u + (unsigned)(wn * 64 + ln15) * 128u + cswz;

  const int nt = K >> 6;

  const int swc = (tid & 7) ^ ((tid >> 3) & 7);
  const __hip_bfloat16* baseA = A  + (size_t)(bm + (tid >> 3)) * K + swc * 8;
  const __hip_bfloat16* baseB = Bt + (size_t)(bn + (tid >> 3)) * K + swc * 8;
  const unsigned ldst0 = (unsigned)(tid * 16);

  auto stageA = [&](int kt, int half) {
    char* dst = lds + ((kt & 1) * 49152) + half * 8192;
    gload16(baseA + (size_t)((half * 64) * K + kt * 64), dst + ldst0);
  };
  auto stageB = [&](int kt, int half) {
    char* dst = lds + ((kt & 1) * 49152) + 16384 + half * 16384;
#pragma unroll
    for (int q = 0; q < 2; ++q) {
      gload16(baseB + (size_t)((half * 128 + q * 64) * K + kt * 64),
              dst + q * 8192 + ldst0);
    }
  };

  f32x4 acc[4][4] = {};
  short8 aLo[2][2], aHi[2][2], b0v[2][2], b1v[2][2];

  // prologue
  stageB(0, 0); stageA(0, 0); stageB(0, 1); stageA(0, 1);
  if (nt > 1) {
    stageB(1, 0); stageA(1, 0);
    asm volatile("s_waitcnt vmcnt(3)");
  } else {
    asm volatile("s_waitcnt vmcnt(0)");
  }
  BAR();
#pragma unroll
  for (int mi = 0; mi < 2; ++mi) {
    unsigned ad = arow0 + (unsigned)(mi * 2048);
    aLo[mi][0] = dsr(ad); aLo[mi][1] = dsr(ad ^ 64u);
  }

  for (int t = 0; t < nt; ++t) {
    const unsigned po = (unsigned)(t & 1) * 49152u;
    const unsigned pn = po ^ 49152u;

    // ---- P1 ----
    asm volatile("s_waitcnt lgkmcnt(0)");
    SB0();
#pragma unroll
    for (int nj = 0; nj < 2; ++nj) b0v[nj][0] = dsr(brow0 + po + (unsigned)(nj * 2048));
#pragma unroll
    for (int nj = 0; nj < 2; ++nj) b0v[nj][1] = dsr((brow0 + po + (unsigned)(nj * 2048)) ^ 64u);
#pragma unroll
    for (int nj = 0; nj < 2; ++nj) b1v[nj][0] = dsr(brow0 + po + (unsigned)((nj + 2) * 2048));
#pragma unroll
    for (int nj = 0; nj < 2; ++nj) b1v[nj][1] = dsr((brow0 + po + (unsigned)((nj + 2) * 2048)) ^ 64u);
    if (t + 1 < nt) stageB(t + 1, 1);
    asm volatile("s_waitcnt lgkmcnt(6)");
    SB0();
    PRIO(1);
#pragma unroll
    for (int mi = 0; mi < 2; ++mi)
#pragma unroll
      for (int nj = 0; nj < 2; ++nj)
        acc[mi][nj] = MFMA16(aLo[mi][0], b0v[nj][0], acc[mi][nj]);
    asm volatile("s_waitcnt lgkmcnt(4)");
    SB0();
#pragma unroll
    for (int mi = 0; mi < 2; ++mi)
#pragma unroll
      for (int nj = 0; nj < 2; ++nj)
        acc[mi][nj] = MFMA16(aLo[mi][1], b0v[nj][1], acc[mi][nj]);
    PRIO(0);

    // ---- P2 ----
#pragma unroll
    for (int mi = 0; mi < 2; ++mi) {
      unsigned ad = arow0 + po + (unsigned)((mi + 2) * 2048);
      aHi[mi][0] = dsr(ad); aHi[mi][1] = dsr(ad ^ 64u);
    }
    if (t + 1 < nt) stageA(t + 1, 1);
    asm volatile("s_waitcnt lgkmcnt(4)");
    SB0();
    PRIO(1);
#pragma unroll
    for (int kk = 0; kk < 2; ++kk)
#pragma unroll
      for (int mi = 0; mi < 2; ++mi)
#pragma unroll
        for (int nj = 0; nj < 2; ++nj)
          acc[mi][nj + 2] = MFMA16(aLo[mi][kk], b1v[nj][kk], acc[mi][nj + 2]);
    PRIO(0);
    BAR();

    // ---- P3 ----
    asm volatile("s_waitcnt lgkmcnt(0)");
    SB0();
    PRIO(1);
#pragma unroll
    for (int kk = 0; kk < 2; ++kk)
#pragma unroll
      for (int mi = 0; mi < 2; ++mi)
#pragma unroll
        for (int nj = 0; nj < 2; ++nj)
          acc[mi + 2][nj] = MFMA16(aHi[mi][kk], b0v[nj][kk], acc[mi + 2][nj]);
    PRIO(0);
    if (t + 2 < nt) stageB(t + 2, 0);
    if (t + 2 < nt)      asm volatile("s_waitcnt vmcnt(2)");
    else if (t + 1 < nt) asm volatile("s_waitcnt vmcnt(0)");
    if (t + 1 < nt) BAR();

    // ---- P4 ----
    if (t + 1 < nt) {
#pragma unroll
      for (int mi = 0; mi < 2; ++mi) {
        unsigned ad = arow0 + pn + (unsigned)(mi * 2048);
        aLo[mi][0] = dsr(ad); aLo[mi][1] = dsr(ad ^ 64u);
      }
    }
    SB0();
    PRIO(1);
#pragma unroll
    for (int kk = 0; kk < 2; ++kk)
#pragma unroll
      for (int mi = 0; mi < 2; ++mi)
#pragma unroll
        for (int nj = 0; nj < 2; ++nj)
          acc[mi + 2][nj + 2] = MFMA16(aHi[mi][kk], b1v[nj][kk], acc[mi + 2][nj + 2]);
    PRIO(0);
    if (t + 2 < nt) stageA(t + 2, 0);
  }

  float biasv[4];
#pragma unroll
  for (int nj = 0; nj < 4; ++nj)
    biasv[nj] = bias[bn + wn * 64 + nj * 16 + ln15];

#pragma unroll
  for (int mi = 0; mi < 4; ++mi) {
    int row0 = bm + wm * 64 + mi * 16 + (lane >> 4) * 4;
#pragma unroll
    for (int nj = 0; nj < 4; ++nj) {
      int col = bn + wn * 64 + nj * 16 + ln15;
#pragma unroll
      for (int r = 0; r < 4; ++r) {
        float v = acc[mi][nj][r] + biasv[nj];
        v = v > 0.f ? v : 0.f;
        size_t idx = (size_t)(row0 + r) * N + col;
        Cb[idx] = __float2bfloat16(v);
        if (Cf) Cf[idx] = v;
      }
    }
  }
}

// ---------------------------------------------------------------------------
// m97-structure 128x128 GEMM (L5 only).
// ---------------------------------------------------------------------------
__global__ __launch_bounds__(256, 2) void gemm_bt(
    const __hip_bfloat16* __restrict__ A,
    const __hip_bfloat16* __restrict__ Bt,
    const float* __restrict__ bias,
    __hip_bfloat16* __restrict__ Cb,
    float* __restrict__ Cf,
    int N, int K) {
  __shared__ char lds[32768];

  const int tid  = threadIdx.x;
  const int lane = tid & 63;
  const int wid  = tid >> 6;
  const int wm   = wid >> 1;
  const int wn   = wid & 1;
  const int bm   = blockIdx.y * 128;
  const int bn   = blockIdx.x * 128;

  f32x4 acc[4][4] = {};

  const int srow = tid >> 3;
  const int sk   = (tid & 7) * 8;
  const int kTiles = K >> 6;

  for (int kt = 0; kt < kTiles; ++kt) {
    __syncthreads();
    const __hip_bfloat16* ga = A  + (size_t)(bm + srow) * K + kt * 64 + sk;
    const __hip_bfloat16* gb = Bt + (size_t)(bn + srow) * K + kt * 64 + sk;
#pragma unroll
    for (int p = 0; p < 4; ++p) {
      gload16(ga + (size_t)(p * 32) * K, &lds[p * 4096 + wid * 1024]);
      gload16(gb + (size_t)(p * 32) * K, &lds[16384 + p * 4096 + wid * 1024]);
    }
    __syncthreads();

#pragma unroll
    for (int kk = 0; kk < 2; ++kk) {
      short8 avec[4], bvec[4];
#pragma unroll
      for (int i = 0; i < 4; ++i) {
        int row = wm * 64 + i * 16 + (lane & 15);
        avec[i] = *(const short8*)&lds[row * 128 + kk * 64 + (lane >> 4) * 16];
      }
#pragma unroll
      for (int j = 0; j < 4; ++j) {
        int row = wn * 64 + j * 16 + (lane & 15);
        bvec[j] = *(const short8*)&lds[16384 + row * 128 + kk * 64 + (lane >> 4) * 16];
      }
#pragma unroll
      for (int i = 0; i < 4; ++i)
#pragma unroll
        for (int j = 0; j < 4; ++j)
          acc[i][j] = MFMA16(avec[i], bvec[j], acc[i][j]);
    }
  }

  float biasv[4];
#pragma unroll
  for (int j = 0; j < 4; ++j)
    biasv[j] = bias[bn + wn * 64 + j * 16 + (lane & 15)];

#pragma unroll
  for (int i = 0; i < 4; ++i) {
    int row0 = bm + wm * 64 + i * 16 + (lane >> 4) * 4;
#pragma unroll
    for (int j = 0; j < 4; ++j) {
      int col = bn + wn * 64 + j * 16 + (lane & 15);
#pragma unroll
      for (int r = 0; r < 4; ++r) {
        float v = acc[i][j][r] + biasv[j];
        v = v > 0.f ? v : 0.f;
        size_t idx = (size_t)(row0 + r) * N + col;
        Cb[idx] = __float2bfloat16(v);
        if (Cf) Cf[idx] = v;
      }
    }
  }
}

// ---------------------------------------------------------------------------
// Head: out[r] = sigmoid( sum(wide[r,:]) + dot(D[r,:], Wh[dom[r],:]) + bh[dom[r]] )
// ---------------------------------------------------------------------------
__global__ __launch_bounds__(256) void head_kernel(
    const float* __restrict__ wide,
    const __hip_bfloat16* __restrict__ D,
    const int* __restrict__ dom,
    const float* __restrict__ Wh,
    const float* __restrict__ bh,
    float* __restrict__ out, int B) {
  const int wid  = threadIdx.x >> 6;
  const int lane = threadIdx.x & 63;
  const int row  = blockIdx.x * 4 + wid;
  if (row >= B) return;
  const int dm = dom[row];

  f32x4 wv = ((const f32x4*)(wide + (size_t)row * 256))[lane];
  float tot = wv[0] + wv[1] + wv[2] + wv[3];

  const unsigned short* drow = (const unsigned short*)(D + (size_t)row * 256);
  ushort4 dv = ((const ushort4*)drow)[lane];
  f32x4 hv = ((const f32x4*)(Wh + (size_t)dm * 256))[lane];
  tot += bf_bits2f(dv.x) * hv[0] + bf_bits2f(dv.y) * hv[1] +
         bf_bits2f(dv.z) * hv[2] + bf_bits2f(dv.w) * hv[3];

#pragma unroll
  for (int off = 32; off > 0; off >>= 1) tot += __shfl_xor(tot, off);

  if (lane == 0) {
    float x = tot + bh[dm];
    out[row] = 1.f / (1.f + __expf(-x));
  }
}

// ---------------------------------------------------------------------------
extern "C" void kernel_launch(void* const* d_in, const int* in_sizes, int n_in,
                              void* d_out, int out_size, void* d_ws, size_t ws_size,
                              hipStream_t stream) {
  const float* wide = (const float*)d_in[0];
  const float* deep = (const float*)d_in[1];
  const int*   dom  = (const int*)d_in[2];
  const float* W1  = (const float*)d_in[3];
  const float* b1  = (const float*)d_in[4];
  const float* W2  = (const float*)d_in[5];
  const float* b2  = (const float*)d_in[6];
  const float* W3  = (const float*)d_in[7];
  const float* b3  = (const float*)d_in[8];
  const float* Wd1 = (const float*)d_in[9];
  const float* bd1 = (const float*)d_in[10];
  const float* Wd2 = (const float*)d_in[11];
  const float* bd2 = (const float*)d_in[12];
  const float* Wh  = (const float*)d_in[13];
  const float* bh  = (const float*)d_in[14];
  float* out = (float*)d_out;

  const int B = 16384;
  char* ws = (char*)d_ws;
  __hip_bfloat16* buf0 = (__hip_bfloat16*)ws;
  __hip_bfloat16* buf1 = (__hip_bfloat16*)(ws + 33554432ull);
  __hip_bfloat16* W1t  = (__hip_bfloat16*)(ws + 100663296ull);
  __hip_bfloat16* W2t  = W1t + 2048 * 1024;
  __hip_bfloat16* W3t  = W2t + 1024 * 2048;
  __hip_bfloat16* Wd1t = W3t + 512 * 1024;
  __hip_bfloat16* Wd2t = Wd1t + 512 * 512;

  transpose_convert<<<dim3(2048 / 64, 1024 / 64), 256, 0, stream>>>(W1, W1t, 1024, 2048);
  transpose_convert<<<dim3(1024 / 64, 2048 / 64), 256, 0, stream>>>(W2, W2t, 2048, 1024);
  transpose_convert<<<dim3(512 / 64, 1024 / 64), 256, 0, stream>>>(W3, W3t, 1024, 512);
  transpose_convert<<<dim3(512 / 64, 512 / 64), 256, 0, stream>>>(Wd1, Wd1t, 512, 512);
  transpose_convert<<<dim3(256 / 64, 512 / 64), 256, 0, stream>>>(Wd2, Wd2t, 512, 256);

  {
    int n8 = B * 1024 / 8;
    f32_to_bf16<<<(n8 + 255) / 256, 256, 0, stream>>>(deep, (unsigned short*)buf0, n8);
  }

  float* shared_out = out + B;
  float* d_out_f    = out + B + (size_t)B * 512;

  // L1: [B,1024]x[1024,2048] -> H1 (buf1)   [256x256 single-buf, 512 blocks]
  gemm_sb<8, 256><<<dim3(512), 512, 0, stream>>>(
      buf0, W1t, b1, buf1, nullptr, 2048, 1024, 2048 / 256);
  // L2: [B,2048]x[2048,1024] -> H2 (buf0)   [256x128 single-buf, 512 blocks]
  gemm_sb<4, 128><<<dim3(512), 512, 0, stream>>>(
      buf1, W2t, b2, buf0, nullptr, 1024, 2048, 1024 / 128);
  // L3: [B,1024]x[1024,512] -> S (buf1 bf16 + fp32 out)
  gemm_128<<<dim3((B / 128) * (512 / 256)), 512, 0, stream>>>(
      buf0, W3t, b3, buf1, shared_out, 512, 1024, 512 / 256);
  // L4: [B,512]x[512,512] -> T1 (buf0)
  gemm_128<<<dim3((B / 128) * (512 / 256)), 512, 0, stream>>>(
      buf1, Wd1t, bd1, buf0, nullptr, 512, 512, 512 / 256);
  // L5: [B,512]x[512,256] -> D (buf1 bf16 + fp32 out)
  gemm_bt<<<dim3(256 / 128, B / 128), 256, 0, stream>>>(buf0, Wd2t, bd2, buf1, d_out_f, 256, 512);

  head_kernel<<<B / 4, 256, 0, stream>>>(wide, buf1, dom, Wh, bh, out, B);
}

// Round 9
// 218.930 us; speedup vs baseline: 3.0486x; 3.0486x over previous
//
#include <hip/hip_runtime.h>
#include <hip/hip_bf16.h>

// ---------------------------------------------------------------------------
// Wide&Deep forward: 5-layer GEMM chain (bf16 MFMA) + wide-sum + domain head.
// L1/L2: gemm_2c — 256x256, BK=64, 8 waves, dbuf LDS, 2 barriers/K-tile,
//   deep prefetch: ALL of tile t+2 staged in P3/P4(t) (3-4 phase flight).
// L3/L4: gemm_128 — 128x256 variant, same deep-prefetch schedule.
// L5: gemm_l5h — gemm_128 with fused domain-head epilogue (writes d + out).
// ---------------------------------------------------------------------------

typedef __attribute__((ext_vector_type(8))) short short8;
typedef __attribute__((ext_vector_type(4))) float f32x4;

static __device__ __forceinline__ unsigned short f2bf_bits(float x) {
  __hip_bfloat16 h = __float2bfloat16(x);
  return __builtin_bit_cast(unsigned short, h);
}
static __device__ __forceinline__ float bf_bits2f(unsigned short u) {
  __hip_bfloat16 h = __builtin_bit_cast(__hip_bfloat16, u);
  return __bfloat162float(h);
}

static __device__ __forceinline__ void gload16(const void* g, void* l) {
  __builtin_amdgcn_global_load_lds(
      (const __attribute__((address_space(1))) void*)g,
      (__attribute__((address_space(3))) void*)l, 16, 0, 0);
}

static __device__ __forceinline__ unsigned lds_u32(const void* p) {
  return (unsigned)(uintptr_t)(const __attribute__((address_space(3))) void*)p;
}

// compiler-invisible LDS read (gemm_128 family)
static __device__ __forceinline__ short8 dsr(unsigned addr) {
  short8 r;
  asm volatile("ds_read_b128 %0, %1" : "=v"(r) : "v"(addr));
  return r;
}

#define MFMA16(a, b, c) __builtin_amdgcn_mfma_f32_16x16x32_bf16((a), (b), (c), 0, 0, 0)
#define SB0() __builtin_amdgcn_sched_barrier(0)
#define PRIO(x) __builtin_amdgcn_s_setprio(x)
#define BAR() __builtin_amdgcn_s_barrier()
#define MEMFENCE() asm volatile("" ::: "memory")

// ---------------------------------------------------------------------------
// Transpose-convert: W [K][N] f32 -> Wt [N][K] bf16
// ---------------------------------------------------------------------------
__global__ void transpose_convert(const float* __restrict__ W,
                                  __hip_bfloat16* __restrict__ Wt,
                                  int K, int N) {
  __shared__ float tile[64][65];
  const int k0 = blockIdx.y * 64;
  const int n0 = blockIdx.x * 64;
  const int t  = threadIdx.x;
  const int tn = t & 63;
  const int t4 = t >> 6;
#pragma unroll
  for (int p = 0; p < 16; ++p) {
    int kl = p * 4 + t4;
    tile[kl][tn] = W[(size_t)(k0 + kl) * N + (n0 + tn)];
  }
  __syncthreads();
#pragma unroll
  for (int p = 0; p < 16; ++p) {
    int nl = p * 4 + t4;
    Wt[(size_t)(n0 + nl) * K + (k0 + tn)] = __float2bfloat16(tile[tn][nl]);
  }
}

// ---------------------------------------------------------------------------
// f32 -> bf16 bulk convert
// ---------------------------------------------------------------------------
__global__ void f32_to_bf16(const float* __restrict__ in,
                            unsigned short* __restrict__ out, int n8) {
  int i = blockIdx.x * blockDim.x + threadIdx.x;
  if (i >= n8) return;
  const f32x4* p = (const f32x4*)in + (size_t)i * 2;
  f32x4 a = p[0], b = p[1];
  short8 o;
  o[0] = (short)f2bf_bits(a[0]); o[1] = (short)f2bf_bits(a[1]);
  o[2] = (short)f2bf_bits(a[2]); o[3] = (short)f2bf_bits(a[3]);
  o[4] = (short)f2bf_bits(b[0]); o[5] = (short)f2bf_bits(b[1]);
  o[6] = (short)f2bf_bits(b[2]); o[7] = (short)f2bf_bits(b[3]);
  *(short8*)(out + (size_t)i * 8) = o;
}

// ---------------------------------------------------------------------------
// gemm_2c: 256x256, BK=64, 8 waves 2x4, 2 barriers/K-tile, deep prefetch.
// Per tile t:
//  P1: read b1(t); Q1 = aLo x b0 (read @P4(t-1))
//  P2: read aHi(t); Q2 = aLo x b1; BARRIER-A
//  P3: Q3 = aHi x b0; stage B0,B1(t+2); vmcnt(4) publish t+1; BARRIER-B
//  P4: read aLo,b0(t+1); Q4 = aHi x b1; stage A0,A1(t+2)
// WAR certs: B(t+2)@P3(t) into buf(po): b0v(t)[@P4(t-1)],b1v(t)[@P1(t)]
//   retired per-wave pre-Q1/Q2, certified by BAR-A(t). A(t+2)@P4(t):
//   aLo(t)[BAR-A(t)], aHi(t)[@P2(t), cert BAR-B(t)]. RAW: publish queue =
//   B(t+1)@P3(t-1):4 + A(t+1)@P4(t-1):4 + B(t+2)@P3(t):4 = 12; vmcnt(4)
//   retires exactly t+1's 8. Prologue: t0+t1 fully staged, vmcnt(8).
// ---------------------------------------------------------------------------
__global__ __launch_bounds__(512, 2) void gemm_2c(
    const __hip_bfloat16* __restrict__ A,
    const __hip_bfloat16* __restrict__ Bt,
    const float* __restrict__ bias,
    __hip_bfloat16* __restrict__ Cb,
    float* __restrict__ Cf,
    int N, int K, int nbx) {
  __shared__ char lds[131072];

  const int tid  = threadIdx.x;
  const int lane = tid & 63;
  const int wid  = tid >> 6;
  const int wm   = wid >> 2;
  const int wn   = wid & 3;

  const int nwg = gridDim.x;
  const int cpx = nwg >> 3;
  const int id  = blockIdx.x;
  const int swz = (id & 7) * cpx + (id >> 3);
  const int bm  = (swz / nbx) * 256;
  const int bn  = (swz % nbx) * 256;

  const int ln15 = lane & 15;
  const unsigned cswz = (unsigned)((((lane >> 4) ^ (lane & 7)) << 4));

  const unsigned aoff = (unsigned)((wm * 128 + ln15) * 128) + cswz;
  const unsigned boff = 32768u + (unsigned)((wn * 64 + ln15) * 128) + cswz;

  const int nt = K >> 6;

  const __hip_bfloat16* baseA = A  + (size_t)(bm + (tid >> 3)) * K +
                                ((tid & 7) ^ ((tid >> 3) & 7)) * 8;
  const __hip_bfloat16* baseB = Bt + (size_t)(bn + (tid >> 3)) * K +
                                ((tid & 7) ^ ((tid >> 3) & 7)) * 8;
  const unsigned ldst0 = (unsigned)(wid * 1024);

  auto stage = [&](int kt, int half, int isB) {
    const __hip_bfloat16* base = isB ? baseB : baseA;
    char* dst = lds + ((kt & 1) * 65536) + (isB ? 32768 : 0) + half * 16384;
#pragma unroll
    for (int q = 0; q < 2; ++q) {
      gload16(base + (size_t)((half * 128 + q * 64) * K + kt * 64),
              dst + q * 8192 + ldst0);
    }
  };

  auto LD = [&](unsigned off) -> short8 {
    return *(const short8*)&lds[off];
  };

  f32x4 acc[8][4] = {};
  short8 aLo[4][2], aHi[4][2], b0v[2][2], b1v[2][2];

  // prologue: tile0 fully + tile1 fully; publish tile0
  stage(0, 0, 1); stage(0, 1, 1); stage(0, 0, 0); stage(0, 1, 0);
  if (nt > 1) {
    stage(1, 0, 1); stage(1, 1, 1); stage(1, 0, 0); stage(1, 1, 0);
    asm volatile("s_waitcnt vmcnt(8)");
  } else {
    asm volatile("s_waitcnt vmcnt(0)");
  }
  BAR();
  MEMFENCE();
  // initial reads: aLo(0), b0(0)
#pragma unroll
  for (int mi = 0; mi < 4; ++mi)
#pragma unroll
    for (int kk = 0; kk < 2; ++kk)
      aLo[mi][kk] = LD((aoff + (unsigned)(mi * 2048)) ^ (unsigned)(kk << 6));
#pragma unroll
  for (int nj = 0; nj < 2; ++nj)
#pragma unroll
    for (int kk = 0; kk < 2; ++kk)
      b0v[nj][kk] = LD((boff + (unsigned)(nj * 2048)) ^ (unsigned)(kk << 6));

  for (int t = 0; t < nt; ++t) {
    const unsigned po = (unsigned)(t & 1) * 65536u;
    const unsigned pn = po ^ 65536u;

    // ---- P1: read b1(t); Q1 = aLo x b0 ----
#pragma unroll
    for (int nj = 0; nj < 2; ++nj)
#pragma unroll
      for (int kk = 0; kk < 2; ++kk)
        b1v[nj][kk] = LD((po + boff + (unsigned)((nj + 2) * 2048)) ^ (unsigned)(kk << 6));
    PRIO(1);
#pragma unroll
    for (int kk = 0; kk < 2; ++kk)
#pragma unroll
      for (int mi = 0; mi < 4; ++mi)
#pragma unroll
        for (int nj = 0; nj < 2; ++nj)
          acc[mi][nj] = MFMA16(aLo[mi][kk], b0v[nj][kk], acc[mi][nj]);
    PRIO(0);

    // ---- P2: read aHi(t); Q2 = aLo x b1; BARRIER-A ----
#pragma unroll
    for (int mi = 0; mi < 4; ++mi)
#pragma unroll
      for (int kk = 0; kk < 2; ++kk)
        aHi[mi][kk] = LD((po + aoff + (unsigned)((mi + 4) * 2048)) ^ (unsigned)(kk << 6));
    PRIO(1);
#pragma unroll
    for (int kk = 0; kk < 2; ++kk)
#pragma unroll
      for (int mi = 0; mi < 4; ++mi)
#pragma unroll
        for (int nj = 0; nj < 2; ++nj)
          acc[mi][nj + 2] = MFMA16(aLo[mi][kk], b1v[nj][kk], acc[mi][nj + 2]);
    PRIO(0);
    BAR();
    MEMFENCE();

    // ---- P3: Q3 = aHi x b0; stage B0,B1(t+2); publish t+1; BARRIER-B ----
    PRIO(1);
#pragma unroll
    for (int kk = 0; kk < 2; ++kk)
#pragma unroll
      for (int mi = 0; mi < 4; ++mi)
#pragma unroll
        for (int nj = 0; nj < 2; ++nj)
          acc[mi + 4][nj] = MFMA16(aHi[mi][kk], b0v[nj][kk], acc[mi + 4][nj]);
    PRIO(0);
    if (t + 2 < nt) { stage(t + 2, 0, 1); stage(t + 2, 1, 1); }
    if (t + 1 < nt) {
      if (t + 2 < nt) asm volatile("s_waitcnt vmcnt(4)");
      else            asm volatile("s_waitcnt vmcnt(0)");
      BAR();
      MEMFENCE();
    }

    // ---- P4: read aLo,b0(t+1); Q4 = aHi x b1; stage A0,A1(t+2) ----
    if (t + 1 < nt) {
#pragma unroll
      for (int mi = 0; mi < 4; ++mi)
#pragma unroll
        for (int kk = 0; kk < 2; ++kk)
          aLo[mi][kk] = LD((pn + aoff + (unsigned)(mi * 2048)) ^ (unsigned)(kk << 6));
#pragma unroll
      for (int nj = 0; nj < 2; ++nj)
#pragma unroll
        for (int kk = 0; kk < 2; ++kk)
          b0v[nj][kk] = LD((pn + boff + (unsigned)(nj * 2048)) ^ (unsigned)(kk << 6));
    }
    PRIO(1);
#pragma unroll
    for (int kk = 0; kk < 2; ++kk)
#pragma unroll
      for (int mi = 0; mi < 4; ++mi)
#pragma unroll
        for (int nj = 0; nj < 2; ++nj)
          acc[mi + 4][nj + 2] = MFMA16(aHi[mi][kk], b1v[nj][kk], acc[mi + 4][nj + 2]);
    PRIO(0);
    if (t + 2 < nt) { stage(t + 2, 0, 0); stage(t + 2, 1, 0); }
  }

  float biasv[4];
#pragma unroll
  for (int nj = 0; nj < 4; ++nj)
    biasv[nj] = bias[bn + wn * 64 + nj * 16 + ln15];

#pragma unroll
  for (int mi = 0; mi < 8; ++mi) {
    int row0 = bm + wm * 128 + mi * 16 + (lane >> 4) * 4;
#pragma unroll
    for (int nj = 0; nj < 4; ++nj) {
      int col = bn + wn * 64 + nj * 16 + ln15;
#pragma unroll
      for (int r = 0; r < 4; ++r) {
        float v = acc[mi][nj][r] + biasv[nj];
        v = v > 0.f ? v : 0.f;
        size_t idx = (size_t)(row0 + r) * N + col;
        Cb[idx] = __float2bfloat16(v);
        if (Cf) Cf[idx] = v;
      }
    }
  }
}

// ---------------------------------------------------------------------------
// gemm_128: 128x256, BK=64, 8 waves 2x4 (wave tile 64x64), 2-barrier deep-
// prefetch schedule (asm reads). Loads/tile = 6; publish vmcnt(4); prologue
// vmcnt(6). Stage all of t+2 in P3 (B) / P4 (A).
// ---------------------------------------------------------------------------
__global__ __launch_bounds__(512, 2) void gemm_128(
    const __hip_bfloat16* __restrict__ A,
    const __hip_bfloat16* __restrict__ Bt,
    const float* __restrict__ bias,
    __hip_bfloat16* __restrict__ Cb,
    float* __restrict__ Cf,
    int N, int K, int nbx) {
  __shared__ char lds[98304];

  const int tid  = threadIdx.x;
  const int lane = tid & 63;
  const int wid  = tid >> 6;
  const int wm   = wid >> 2;
  const int wn   = wid & 3;

  const int nwg = gridDim.x;
  const int cpx = nwg >> 3;
  const int id  = blockIdx.x;
  const int swz = (id & 7) * cpx + (id >> 3);
  const int bm  = (swz / nbx) * 128;
  const int bn  = (swz % nbx) * 256;

  const int ln15 = lane & 15;
  const unsigned cswz = (unsigned)((((lane >> 4) ^ (lane & 7)) << 4));

  const unsigned lbase = lds_u32(lds);
  const unsigned arow0 = lbase + (unsigned)(wm * 64 + ln15) * 128u + cswz;
  const unsigned brow0 = lbase + 16384u + (unsigned)(wn * 64 + ln15) * 128u + cswz;

  const int nt = K >> 6;

  const int swc = (tid & 7) ^ ((tid >> 3) & 7);
  const __hip_bfloat16* baseA = A  + (size_t)(bm + (tid >> 3)) * K + swc * 8;
  const __hip_bfloat16* baseB = Bt + (size_t)(bn + (tid >> 3)) * K + swc * 8;
  const unsigned ldst0 = (unsigned)(tid * 16);

  auto stageA = [&](int kt, int half) {
    char* dst = lds + ((kt & 1) * 49152) + half * 8192;
    gload16(baseA + (size_t)((half * 64) * K + kt * 64), dst + ldst0);
  };
  auto stageB = [&](int kt, int half) {
    char* dst = lds + ((kt & 1) * 49152) + 16384 + half * 16384;
#pragma unroll
    for (int q = 0; q < 2; ++q) {
      gload16(baseB + (size_t)((half * 128 + q * 64) * K + kt * 64),
              dst + q * 8192 + ldst0);
    }
  };

  f32x4 acc[4][4] = {};
  short8 aLo[2][2], aHi[2][2], b0v[2][2], b1v[2][2];

  // prologue: tile0 fully + tile1 fully
  stageB(0, 0); stageB(0, 1); stageA(0, 0); stageA(0, 1);
  if (nt > 1) {
    stageB(1, 0); stageB(1, 1); stageA(1, 0); stageA(1, 1);
    asm volatile("s_waitcnt vmcnt(6)");
  } else {
    asm volatile("s_waitcnt vmcnt(0)");
  }
  BAR();
#pragma unroll
  for (int mi = 0; mi < 2; ++mi) {
    unsigned ad = arow0 + (unsigned)(mi * 2048);
    aLo[mi][0] = dsr(ad); aLo[mi][1] = dsr(ad ^ 64u);
  }

  for (int t = 0; t < nt; ++t) {
    const unsigned po = (unsigned)(t & 1) * 49152u;
    const unsigned pn = po ^ 49152u;

    // ---- P1: read b0,b1(t); Q1 = aLo x b0 (counted gates) ----
    asm volatile("s_waitcnt lgkmcnt(0)");
    SB0();
#pragma unroll
    for (int nj = 0; nj < 2; ++nj) b0v[nj][0] = dsr(brow0 + po + (unsigned)(nj * 2048));
#pragma unroll
    for (int nj = 0; nj < 2; ++nj) b0v[nj][1] = dsr((brow0 + po + (unsigned)(nj * 2048)) ^ 64u);
#pragma unroll
    for (int nj = 0; nj < 2; ++nj) b1v[nj][0] = dsr(brow0 + po + (unsigned)((nj + 2) * 2048));
#pragma unroll
    for (int nj = 0; nj < 2; ++nj) b1v[nj][1] = dsr((brow0 + po + (unsigned)((nj + 2) * 2048)) ^ 64u);
    asm volatile("s_waitcnt lgkmcnt(6)");
    SB0();
    PRIO(1);
#pragma unroll
    for (int mi = 0; mi < 2; ++mi)
#pragma unroll
      for (int nj = 0; nj < 2; ++nj)
        acc[mi][nj] = MFMA16(aLo[mi][0], b0v[nj][0], acc[mi][nj]);
    asm volatile("s_waitcnt lgkmcnt(4)");
    SB0();
#pragma unroll
    for (int mi = 0; mi < 2; ++mi)
#pragma unroll
      for (int nj = 0; nj < 2; ++nj)
        acc[mi][nj] = MFMA16(aLo[mi][1], b0v[nj][1], acc[mi][nj]);
    PRIO(0);

    // ---- P2: read aHi(t); Q2 = aLo x b1; BARRIER-A ----
#pragma unroll
    for (int mi = 0; mi < 2; ++mi) {
      unsigned ad = arow0 + po + (unsigned)((mi + 2) * 2048);
      aHi[mi][0] = dsr(ad); aHi[mi][1] = dsr(ad ^ 64u);
    }
    asm volatile("s_waitcnt lgkmcnt(4)");
    SB0();
    PRIO(1);
#pragma unroll
    for (int kk = 0; kk < 2; ++kk)
#pragma unroll
      for (int mi = 0; mi < 2; ++mi)
#pragma unroll
        for (int nj = 0; nj < 2; ++nj)
          acc[mi][nj + 2] = MFMA16(aLo[mi][kk], b1v[nj][kk], acc[mi][nj + 2]);
    PRIO(0);
    BAR();

    // ---- P3: Q3 = aHi x b0; stage B(t+2); publish t+1; BARRIER-B ----
    asm volatile("s_waitcnt lgkmcnt(0)");
    SB0();
    PRIO(1);
#pragma unroll
    for (int kk = 0; kk < 2; ++kk)
#pragma unroll
      for (int mi = 0; mi < 2; ++mi)
#pragma unroll
        for (int nj = 0; nj < 2; ++nj)
          acc[mi + 2][nj] = MFMA16(aHi[mi][kk], b0v[nj][kk], acc[mi + 2][nj]);
    PRIO(0);
    if (t + 2 < nt) { stageB(t + 2, 0); stageB(t + 2, 1); }
    if (t + 1 < nt) {
      if (t + 2 < nt) asm volatile("s_waitcnt vmcnt(4)");
      else            asm volatile("s_waitcnt vmcnt(0)");
      BAR();
    }

    // ---- P4: read aLo(t+1); Q4 = aHi x b1; stage A(t+2) ----
    if (t + 1 < nt) {
#pragma unroll
      for (int mi = 0; mi < 2; ++mi) {
        unsigned ad = arow0 + pn + (unsigned)(mi * 2048);
        aLo[mi][0] = dsr(ad); aLo[mi][1] = dsr(ad ^ 64u);
      }
    }
    SB0();
    PRIO(1);
#pragma unroll
    for (int kk = 0; kk < 2; ++kk)
#pragma unroll
      for (int mi = 0; mi < 2; ++mi)
#pragma unroll
        for (int nj = 0; nj < 2; ++nj)
          acc[mi + 2][nj + 2] = MFMA16(aHi[mi][kk], b1v[nj][kk], acc[mi + 2][nj + 2]);
    PRIO(0);
    if (t + 2 < nt) { stageA(t + 2, 0); stageA(t + 2, 1); }
  }

  float biasv[4];
#pragma unroll
  for (int nj = 0; nj < 4; ++nj)
    biasv[nj] = bias[bn + wn * 64 + nj * 16 + ln15];

#pragma unroll
  for (int mi = 0; mi < 4; ++mi) {
    int row0 = bm + wm * 64 + mi * 16 + (lane >> 4) * 4;
#pragma unroll
    for (int nj = 0; nj < 4; ++nj) {
      int col = bn + wn * 64 + nj * 16 + ln15;
#pragma unroll
      for (int r = 0; r < 4; ++r) {
        float v = acc[mi][nj][r] + biasv[nj];
        v = v > 0.f ? v : 0.f;
        size_t idx = (size_t)(row0 + r) * N + col;
        Cb[idx] = __float2bfloat16(v);
        if (Cf) Cf[idx] = v;
      }
    }
  }
}

// ---------------------------------------------------------------------------
// gemm_l5h: L5 (128x256, K=512, nbx=1 -> block owns all 256 cols) with fused
// domain head. Writes d fp32 [B,256] and out[r] =
// sigmoid(sum(wide[r,:]) + dot(d[r,:], Wh[dom[r],:]) + bh[dom[r]]).
// ---------------------------------------------------------------------------
__global__ __launch_bounds__(512, 2) void gemm_l5h(
    const __hip_bfloat16* __restrict__ A,
    const __hip_bfloat16* __restrict__ Bt,
    const float* __restrict__ bias,
    float* __restrict__ Df,
    const float* __restrict__ wide,
    const int* __restrict__ dom,
    const float* __restrict__ Wh,
    const float* __restrict__ bh,
    float* __restrict__ outp,
    int K) {
  __shared__ char lds[98304];

  const int tid  = threadIdx.x;
  const int lane = tid & 63;
  const int wid  = tid >> 6;
  const int wm   = wid >> 2;
  const int wn   = wid & 3;

  const int nwg = gridDim.x;
  const int cpx = nwg >> 3;
  const int id  = blockIdx.x;
  const int swz = (id & 7) * cpx + (id >> 3);
  const int bm  = swz * 128;

  const int ln15 = lane & 15;
  const unsigned cswz = (unsigned)((((lane >> 4) ^ (lane & 7)) << 4));

  const unsigned lbase = lds_u32(lds);
  const unsigned arow0 = lbase + (unsigned)(wm * 64 + ln15) * 128u + cswz;
  const unsigned brow0 = lbase + 16384u + (unsigned)(wn * 64 + ln15) * 128u + cswz;

  const int nt = K >> 6;

  const int swc = (tid & 7) ^ ((tid >> 3) & 7);
  const __hip_bfloat16* baseA = A  + (size_t)(bm + (tid >> 3)) * K + swc * 8;
  const __hip_bfloat16* baseB = Bt + (size_t)(tid >> 3) * K + swc * 8;
  const unsigned ldst0 = (unsigned)(tid * 16);

  auto stageA = [&](int kt, int half) {
    char* dst = lds + ((kt & 1) * 49152) + half * 8192;
    gload16(baseA + (size_t)((half * 64) * K + kt * 64), dst + ldst0);
  };
  auto stageB = [&](int kt, int half) {
    char* dst = lds + ((kt & 1) * 49152) + 16384 + half * 16384;
#pragma unroll
    for (int q = 0; q < 2; ++q) {
      gload16(baseB + (size_t)((half * 128 + q * 64) * K + kt * 64),
              dst + q * 8192 + ldst0);
    }
  };

  f32x4 acc[4][4] = {};
  short8 aLo[2][2], aHi[2][2], b0v[2][2], b1v[2][2];

  stageB(0, 0); stageB(0, 1); stageA(0, 0); stageA(0, 1);
  if (nt > 1) {
    stageB(1, 0); stageB(1, 1); stageA(1, 0); stageA(1, 1);
    asm volatile("s_waitcnt vmcnt(6)");
  } else {
    asm volatile("s_waitcnt vmcnt(0)");
  }
  BAR();
#pragma unroll
  for (int mi = 0; mi < 2; ++mi) {
    unsigned ad = arow0 + (unsigned)(mi * 2048);
    aLo[mi][0] = dsr(ad); aLo[mi][1] = dsr(ad ^ 64u);
  }

  for (int t = 0; t < nt; ++t) {
    const unsigned po = (unsigned)(t & 1) * 49152u;
    const unsigned pn = po ^ 49152u;

    asm volatile("s_waitcnt lgkmcnt(0)");
    SB0();
#pragma unroll
    for (int nj = 0; nj < 2; ++nj) b0v[nj][0] = dsr(brow0 + po + (unsigned)(nj * 2048));
#pragma unroll
    for (int nj = 0; nj < 2; ++nj) b0v[nj][1] = dsr((brow0 + po + (unsigned)(nj * 2048)) ^ 64u);
#pragma unroll
    for (int nj = 0; nj < 2; ++nj) b1v[nj][0] = dsr(brow0 + po + (unsigned)((nj + 2) * 2048));
#pragma unroll
    for (int nj = 0; nj < 2; ++nj) b1v[nj][1] = dsr((brow0 + po + (unsigned)((nj + 2) * 2048)) ^ 64u);
    asm volatile("s_waitcnt lgkmcnt(6)");
    SB0();
    PRIO(1);
#pragma unroll
    for (int mi = 0; mi < 2; ++mi)
#pragma unroll
      for (int nj = 0; nj < 2; ++nj)
        acc[mi][nj] = MFMA16(aLo[mi][0], b0v[nj][0], acc[mi][nj]);
    asm volatile("s_waitcnt lgkmcnt(4)");
    SB0();
#pragma unroll
    for (int mi = 0; mi < 2; ++mi)
#pragma unroll
      for (int nj = 0; nj < 2; ++nj)
        acc[mi][nj] = MFMA16(aLo[mi][1], b0v[nj][1], acc[mi][nj]);
    PRIO(0);

#pragma unroll
    for (int mi = 0; mi < 2; ++mi) {
      unsigned ad = arow0 + po + (unsigned)((mi + 2) * 2048);
      aHi[mi][0] = dsr(ad); aHi[mi][1] = dsr(ad ^ 64u);
    }
    asm volatile("s_waitcnt lgkmcnt(4)");
    SB0();
    PRIO(1);
#pragma unroll
    for (int kk = 0; kk < 2; ++kk)
#pragma unroll
      for (int mi = 0; mi < 2; ++mi)
#pragma unroll
        for (int nj = 0; nj < 2; ++nj)
          acc[mi][nj + 2] = MFMA16(aLo[mi][kk], b1v[nj][kk], acc[mi][nj + 2]);
    PRIO(0);
    BAR();

    asm volatile("s_waitcnt lgkmcnt(0)");
    SB0();
    PRIO(1);
#pragma unroll
    for (int kk = 0; kk < 2; ++kk)
#pragma unroll
      for (int mi = 0; mi < 2; ++mi)
#pragma unroll
        for (int nj = 0; nj < 2; ++nj)
          acc[mi + 2][nj] = MFMA16(aHi[mi][kk], b0v[nj][kk], acc[mi + 2][nj]);
    PRIO(0);
    if (t + 2 < nt) { stageB(t + 2, 0); stageB(t + 2, 1); }
    if (t + 1 < nt) {
      if (t + 2 < nt) asm volatile("s_waitcnt vmcnt(4)");
      else            asm volatile("s_waitcnt vmcnt(0)");
      BAR();
    }

    if (t + 1 < nt) {
#pragma unroll
      for (int mi = 0; mi < 2; ++mi) {
        unsigned ad = arow0 + pn + (unsigned)(mi * 2048);
        aLo[mi][0] = dsr(ad); aLo[mi][1] = dsr(ad ^ 64u);
      }
    }
    SB0();
    PRIO(1);
#pragma unroll
    for (int kk = 0; kk < 2; ++kk)
#pragma unroll
      for (int mi = 0; mi < 2; ++mi)
#pragma unroll
        for (int nj = 0; nj < 2; ++nj)
          acc[mi + 2][nj + 2] = MFMA16(aHi[mi][kk], b1v[nj][kk], acc[mi + 2][nj + 2]);
    PRIO(0);
    if (t + 2 < nt) { stageA(t + 2, 0); stageA(t + 2, 1); }
  }

  // ---- fused epilogue ----
  BAR();  // all waves' K-loop LDS reads done -> LDS reusable
  MEMFENCE();
  unsigned short* ldsD = (unsigned short*)lds;          // [128][264] bf16
  float* ldsH = (float*)(lds + 128 * 264 * 2);          // [128][4] f32

  float biasv[4];
#pragma unroll
  for (int nj = 0; nj < 4; ++nj)
    biasv[nj] = bias[wn * 64 + nj * 16 + ln15];

#pragma unroll
  for (int mi = 0; mi < 4; ++mi) {
    int lrow0 = wm * 64 + mi * 16 + (lane >> 4) * 4;
#pragma unroll
    for (int nj = 0; nj < 4; ++nj) {
      int col = wn * 64 + nj * 16 + ln15;
#pragma unroll
      for (int r = 0; r < 4; ++r) {
        float v = acc[mi][nj][r] + biasv[nj];
        v = v > 0.f ? v : 0.f;
        Df[(size_t)(bm + lrow0 + r) * 256 + col] = v;
        ldsD[(lrow0 + r) * 264 + col] = f2bf_bits(v);
      }
    }
  }

  // wide-sum for row tid>>2, quarter tid&3 (overlaps with D writes)
  const int erow = tid >> 2;
  const int eq   = tid & 3;
  float s = 0.f;
  {
    const f32x4* wp = (const f32x4*)(wide + (size_t)(bm + erow) * 256 + eq * 64);
#pragma unroll
    for (int j = 0; j < 16; ++j) {
      f32x4 w = wp[j];
      s += w[0] + w[1] + w[2] + w[3];
    }
  }
  BAR();  // ldsD fully written
  MEMFENCE();

  // head dot: quarter of D row (LDS) x Wh[dom]
  const int dm = dom[bm + erow];
  float h = 0.f;
  {
    const f32x4* hp = (const f32x4*)(Wh + (size_t)dm * 256 + eq * 64);
    const short8* dp = (const short8*)(ldsD + erow * 264 + eq * 64);
#pragma unroll
    for (int j = 0; j < 8; ++j) {
      short8 d8 = dp[j];
      f32x4 h0 = hp[j * 2], h1 = hp[j * 2 + 1];
      h += bf_bits2f((unsigned short)d8[0]) * h0[0] +
           bf_bits2f((unsigned short)d8[1]) * h0[1] +
           bf_bits2f((unsigned short)d8[2]) * h0[2] +
           bf_bits2f((unsigned short)d8[3]) * h0[3] +
           bf_bits2f((unsigned short)d8[4]) * h1[0] +
           bf_bits2f((unsigned short)d8[5]) * h1[1] +
           bf_bits2f((unsigned short)d8[6]) * h1[2] +
           bf_bits2f((unsigned short)d8[7]) * h1[3];
    }
  }
  ldsH[erow * 4 + eq] = s + h;
  BAR();
  MEMFENCE();

  if (tid < 128) {
    float val = ldsH[tid * 4] + ldsH[tid * 4 + 1] +
                ldsH[tid * 4 + 2] + ldsH[tid * 4 + 3];
    int dmr = dom[bm + tid];
    float x = val + bh[dmr];
    outp[bm + tid] = 1.f / (1.f + __expf(-x));
  }
}

// ---------------------------------------------------------------------------
extern "C" void kernel_launch(void* const* d_in, const int* in_sizes, int n_in,
                              void* d_out, int out_size, void* d_ws, size_t ws_size,
                              hipStream_t stream) {
  const float* wide = (const float*)d_in[0];
  const float* deep = (const float*)d_in[1];
  const int*   dom  = (const int*)d_in[2];
  const float* W1  = (const float*)d_in[3];
  const float* b1  = (const float*)d_in[4];
  const float* W2  = (const float*)d_in[5];
  const float* b2  = (const float*)d_in[6];
  const float* W3  = (const float*)d_in[7];
  const float* b3  = (const float*)d_in[8];
  const float* Wd1 = (const float*)d_in[9];
  const float* bd1 = (const float*)d_in[10];
  const float* Wd2 = (const float*)d_in[11];
  const float* bd2 = (const float*)d_in[12];
  const float* Wh  = (const float*)d_in[13];
  const float* bh  = (const float*)d_in[14];
  float* out = (float*)d_out;

  const int B = 16384;
  char* ws = (char*)d_ws;
  __hip_bfloat16* buf0 = (__hip_bfloat16*)ws;
  __hip_bfloat16* buf1 = (__hip_bfloat16*)(ws + 33554432ull);
  __hip_bfloat16* W1t  = (__hip_bfloat16*)(ws + 100663296ull);
  __hip_bfloat16* W2t  = W1t + 2048 * 1024;
  __hip_bfloat16* W3t  = W2t + 1024 * 2048;
  __hip_bfloat16* Wd1t = W3t + 512 * 1024;
  __hip_bfloat16* Wd2t = Wd1t + 512 * 512;

  transpose_convert<<<dim3(2048 / 64, 1024 / 64), 256, 0, stream>>>(W1, W1t, 1024, 2048);
  transpose_convert<<<dim3(1024 / 64, 2048 / 64), 256, 0, stream>>>(W2, W2t, 2048, 1024);
  transpose_convert<<<dim3(512 / 64, 1024 / 64), 256, 0, stream>>>(W3, W3t, 1024, 512);
  transpose_convert<<<dim3(512 / 64, 512 / 64), 256, 0, stream>>>(Wd1, Wd1t, 512, 512);
  transpose_convert<<<dim3(256 / 64, 512 / 64), 256, 0, stream>>>(Wd2, Wd2t, 512, 256);

  {
    int n8 = B * 1024 / 8;
    f32_to_bf16<<<(n8 + 255) / 256, 256, 0, stream>>>(deep, (unsigned short*)buf0, n8);
  }

  float* shared_out = out + B;
  float* d_out_f    = out + B + (size_t)B * 512;

  // L1: [B,1024]x[1024,2048] -> H1 (buf1)
  gemm_2c<<<dim3((2048 / 256) * (B / 256)), 512, 0, stream>>>(
      buf0, W1t, b1, buf1, nullptr, 2048, 1024, 2048 / 256);
  // L2: [B,2048]x[2048,1024] -> H2 (buf0)
  gemm_2c<<<dim3((1024 / 256) * (B / 256)), 512, 0, stream>>>(
      buf1, W2t, b2, buf0, nullptr, 1024, 2048, 1024 / 256);
  // L3: [B,1024]x[1024,512] -> S (buf1 bf16 + fp32 out)
  gemm_128<<<dim3((B / 128) * (512 / 256)), 512, 0, stream>>>(
      buf0, W3t, b3, buf1, shared_out, 512, 1024, 512 / 256);
  // L4: [B,512]x[512,512] -> T1 (buf0)
  gemm_128<<<dim3((B / 128) * (512 / 256)), 512, 0, stream>>>(
      buf1, Wd1t, bd1, buf0, nullptr, 512, 512, 512 / 256);
  // L5 + head: [B,512]x[512,256] -> d (fp32 out) + out
  gemm_l5h<<<dim3(B / 128), 512, 0, stream>>>(
      buf0, Wd2t, bd2, d_out_f, wide, dom, Wh, bh, out, 512);
}

// Round 10
// 218.110 us; speedup vs baseline: 3.0601x; 1.0038x over previous
//
#include <hip/hip_runtime.h>
#include <hip/hip_bf16.h>

// ---------------------------------------------------------------------------
// Wide&Deep forward: 5-layer GEMM chain (bf16 MFMA) + wide-sum + domain head.
// prep: fused deep-convert + 5 weight transposes (1 launch).
// L1: gemm_2c (16x16x32, R9 control). L2: gemm_2c32 (32x32x16, same skeleton).
// L3/L4: gemm_128. L5: gemm_l5h (fused domain head).
// ---------------------------------------------------------------------------

typedef __attribute__((ext_vector_type(8))) short short8;
typedef __attribute__((ext_vector_type(4))) float f32x4;
typedef __attribute__((ext_vector_type(16))) float f32x16;

static __device__ __forceinline__ unsigned short f2bf_bits(float x) {
  __hip_bfloat16 h = __float2bfloat16(x);
  return __builtin_bit_cast(unsigned short, h);
}
static __device__ __forceinline__ float bf_bits2f(unsigned short u) {
  __hip_bfloat16 h = __builtin_bit_cast(__hip_bfloat16, u);
  return __bfloat162float(h);
}

static __device__ __forceinline__ void gload16(const void* g, void* l) {
  __builtin_amdgcn_global_load_lds(
      (const __attribute__((address_space(1))) void*)g,
      (__attribute__((address_space(3))) void*)l, 16, 0, 0);
}

static __device__ __forceinline__ unsigned lds_u32(const void* p) {
  return (unsigned)(uintptr_t)(const __attribute__((address_space(3))) void*)p;
}

// compiler-invisible LDS read (gemm_128 family)
static __device__ __forceinline__ short8 dsr(unsigned addr) {
  short8 r;
  asm volatile("ds_read_b128 %0, %1" : "=v"(r) : "v"(addr));
  return r;
}

#define MFMA16(a, b, c) __builtin_amdgcn_mfma_f32_16x16x32_bf16((a), (b), (c), 0, 0, 0)
#define MFMA32(a, b, c) __builtin_amdgcn_mfma_f32_32x32x16_bf16((a), (b), (c), 0, 0, 0)
#define SB0() __builtin_amdgcn_sched_barrier(0)
#define PRIO(x) __builtin_amdgcn_s_setprio(x)
#define BAR() __builtin_amdgcn_s_barrier()
#define MEMFENCE() asm volatile("" ::: "memory")

// ---------------------------------------------------------------------------
// prep: fused preprocessing.
// blocks [0,8192): deep f32->bf16 (8 elems/thread)
// blocks [8192,9440): 64x64 transpose tiles of W1,W2,W3,Wd1,Wd2
// ---------------------------------------------------------------------------
__global__ __launch_bounds__(256) void prep(
    const float* __restrict__ deep, unsigned short* __restrict__ deepb,
    const float* __restrict__ W1, __hip_bfloat16* __restrict__ W1t,
    const float* __restrict__ W2, __hip_bfloat16* __restrict__ W2t,
    const float* __restrict__ W3, __hip_bfloat16* __restrict__ W3t,
    const float* __restrict__ Wd1, __hip_bfloat16* __restrict__ Wd1t,
    const float* __restrict__ Wd2, __hip_bfloat16* __restrict__ Wd2t) {
  __shared__ float tile[64][65];
  int blk = blockIdx.x;
  if (blk < 8192) {
    int i = blk * 256 + threadIdx.x;
    const f32x4* p = (const f32x4*)deep + (size_t)i * 2;
    f32x4 a = p[0], b = p[1];
    short8 o;
    o[0] = (short)f2bf_bits(a[0]); o[1] = (short)f2bf_bits(a[1]);
    o[2] = (short)f2bf_bits(a[2]); o[3] = (short)f2bf_bits(a[3]);
    o[4] = (short)f2bf_bits(b[0]); o[5] = (short)f2bf_bits(b[1]);
    o[6] = (short)f2bf_bits(b[2]); o[7] = (short)f2bf_bits(b[3]);
    *(short8*)(deepb + (size_t)i * 8) = o;
    return;
  }
  blk -= 8192;
  const float* W; __hip_bfloat16* Wt; int K, N;
  if (blk < 512)       {             W = W1;  Wt = W1t;  K = 1024; N = 2048; }
  else if (blk < 1024) { blk -= 512;  W = W2;  Wt = W2t;  K = 2048; N = 1024; }
  else if (blk < 1152) { blk -= 1024; W = W3;  Wt = W3t;  K = 1024; N = 512; }
  else if (blk < 1216) { blk -= 1152; W = Wd1; Wt = Wd1t; K = 512;  N = 512; }
  else                 { blk -= 1216; W = Wd2; Wt = Wd2t; K = 512;  N = 256; }
  const int ntx = N >> 6;
  const int k0 = (blk / ntx) * 64;
  const int n0 = (blk % ntx) * 64;
  const int t  = threadIdx.x;
  const int tn = t & 63;
  const int t4 = t >> 6;
#pragma unroll
  for (int p = 0; p < 16; ++p) {
    int kl = p * 4 + t4;
    tile[kl][tn] = W[(size_t)(k0 + kl) * N + (n0 + tn)];
  }
  __syncthreads();
#pragma unroll
  for (int p = 0; p < 16; ++p) {
    int nl = p * 4 + t4;
    Wt[(size_t)(n0 + nl) * K + (k0 + tn)] = __float2bfloat16(tile[tn][nl]);
  }
}

// ---------------------------------------------------------------------------
// gemm_2c: 256x256, BK=64, 8 waves 2x4, 16x16x32 MFMA, R9 schedule (control).
// ---------------------------------------------------------------------------
__global__ __launch_bounds__(512, 2) void gemm_2c(
    const __hip_bfloat16* __restrict__ A,
    const __hip_bfloat16* __restrict__ Bt,
    const float* __restrict__ bias,
    __hip_bfloat16* __restrict__ Cb,
    float* __restrict__ Cf,
    int N, int K, int nbx) {
  __shared__ char lds[131072];

  const int tid  = threadIdx.x;
  const int lane = tid & 63;
  const int wid  = tid >> 6;
  const int wm   = wid >> 2;
  const int wn   = wid & 3;

  const int nwg = gridDim.x;
  const int cpx = nwg >> 3;
  const int id  = blockIdx.x;
  const int swz = (id & 7) * cpx + (id >> 3);
  const int bm  = (swz / nbx) * 256;
  const int bn  = (swz % nbx) * 256;

  const int ln15 = lane & 15;
  const unsigned cswz = (unsigned)((((lane >> 4) ^ (lane & 7)) << 4));

  const unsigned aoff = (unsigned)((wm * 128 + ln15) * 128) + cswz;
  const unsigned boff = 32768u + (unsigned)((wn * 64 + ln15) * 128) + cswz;

  const int nt = K >> 6;

  const __hip_bfloat16* baseA = A  + (size_t)(bm + (tid >> 3)) * K +
                                ((tid & 7) ^ ((tid >> 3) & 7)) * 8;
  const __hip_bfloat16* baseB = Bt + (size_t)(bn + (tid >> 3)) * K +
                                ((tid & 7) ^ ((tid >> 3) & 7)) * 8;
  const unsigned ldst0 = (unsigned)(wid * 1024);

  auto stage = [&](int kt, int half, int isB) {
    const __hip_bfloat16* base = isB ? baseB : baseA;
    char* dst = lds + ((kt & 1) * 65536) + (isB ? 32768 : 0) + half * 16384;
#pragma unroll
    for (int q = 0; q < 2; ++q) {
      gload16(base + (size_t)((half * 128 + q * 64) * K + kt * 64),
              dst + q * 8192 + ldst0);
    }
  };

  auto LD = [&](unsigned off) -> short8 {
    return *(const short8*)&lds[off];
  };

  f32x4 acc[8][4] = {};
  short8 aLo[4][2], aHi[4][2], b0v[2][2], b1v[2][2];

  stage(0, 0, 1); stage(0, 1, 1); stage(0, 0, 0); stage(0, 1, 0);
  if (nt > 1) {
    stage(1, 0, 1); stage(1, 1, 1); stage(1, 0, 0); stage(1, 1, 0);
    asm volatile("s_waitcnt vmcnt(8)");
  } else {
    asm volatile("s_waitcnt vmcnt(0)");
  }
  BAR();
  MEMFENCE();
#pragma unroll
  for (int mi = 0; mi < 4; ++mi)
#pragma unroll
    for (int kk = 0; kk < 2; ++kk)
      aLo[mi][kk] = LD((aoff + (unsigned)(mi * 2048)) ^ (unsigned)(kk << 6));
#pragma unroll
  for (int nj = 0; nj < 2; ++nj)
#pragma unroll
    for (int kk = 0; kk < 2; ++kk)
      b0v[nj][kk] = LD((boff + (unsigned)(nj * 2048)) ^ (unsigned)(kk << 6));

  for (int t = 0; t < nt; ++t) {
    const unsigned po = (unsigned)(t & 1) * 65536u;
    const unsigned pn = po ^ 65536u;

    // ---- P1 ----
#pragma unroll
    for (int nj = 0; nj < 2; ++nj)
#pragma unroll
      for (int kk = 0; kk < 2; ++kk)
        b1v[nj][kk] = LD((po + boff + (unsigned)((nj + 2) * 2048)) ^ (unsigned)(kk << 6));
    PRIO(1);
#pragma unroll
    for (int kk = 0; kk < 2; ++kk)
#pragma unroll
      for (int mi = 0; mi < 4; ++mi)
#pragma unroll
        for (int nj = 0; nj < 2; ++nj)
          acc[mi][nj] = MFMA16(aLo[mi][kk], b0v[nj][kk], acc[mi][nj]);
    PRIO(0);

    // ---- P2 ----
#pragma unroll
    for (int mi = 0; mi < 4; ++mi)
#pragma unroll
      for (int kk = 0; kk < 2; ++kk)
        aHi[mi][kk] = LD((po + aoff + (unsigned)((mi + 4) * 2048)) ^ (unsigned)(kk << 6));
    PRIO(1);
#pragma unroll
    for (int kk = 0; kk < 2; ++kk)
#pragma unroll
      for (int mi = 0; mi < 4; ++mi)
#pragma unroll
        for (int nj = 0; nj < 2; ++nj)
          acc[mi][nj + 2] = MFMA16(aLo[mi][kk], b1v[nj][kk], acc[mi][nj + 2]);
    PRIO(0);
    BAR();
    MEMFENCE();

    // ---- P3 ----
    PRIO(1);
#pragma unroll
    for (int kk = 0; kk < 2; ++kk)
#pragma unroll
      for (int mi = 0; mi < 4; ++mi)
#pragma unroll
        for (int nj = 0; nj < 2; ++nj)
          acc[mi + 4][nj] = MFMA16(aHi[mi][kk], b0v[nj][kk], acc[mi + 4][nj]);
    PRIO(0);
    if (t + 2 < nt) { stage(t + 2, 0, 1); stage(t + 2, 1, 1); }
    if (t + 1 < nt) {
      if (t + 2 < nt) asm volatile("s_waitcnt vmcnt(4)");
      else            asm volatile("s_waitcnt vmcnt(0)");
      BAR();
      MEMFENCE();
    }

    // ---- P4 ----
    if (t + 1 < nt) {
#pragma unroll
      for (int mi = 0; mi < 4; ++mi)
#pragma unroll
        for (int kk = 0; kk < 2; ++kk)
          aLo[mi][kk] = LD((pn + aoff + (unsigned)(mi * 2048)) ^ (unsigned)(kk << 6));
#pragma unroll
      for (int nj = 0; nj < 2; ++nj)
#pragma unroll
        for (int kk = 0; kk < 2; ++kk)
          b0v[nj][kk] = LD((pn + boff + (unsigned)(nj * 2048)) ^ (unsigned)(kk << 6));
    }
    PRIO(1);
#pragma unroll
    for (int kk = 0; kk < 2; ++kk)
#pragma unroll
      for (int mi = 0; mi < 4; ++mi)
#pragma unroll
        for (int nj = 0; nj < 2; ++nj)
          acc[mi + 4][nj + 2] = MFMA16(aHi[mi][kk], b1v[nj][kk], acc[mi + 4][nj + 2]);
    PRIO(0);
    if (t + 2 < nt) { stage(t + 2, 0, 0); stage(t + 2, 1, 0); }
  }

  float biasv[4];
#pragma unroll
  for (int nj = 0; nj < 4; ++nj)
    biasv[nj] = bias[bn + wn * 64 + nj * 16 + ln15];

#pragma unroll
  for (int mi = 0; mi < 8; ++mi) {
    int row0 = bm + wm * 128 + mi * 16 + (lane >> 4) * 4;
#pragma unroll
    for (int nj = 0; nj < 4; ++nj) {
      int col = bn + wn * 64 + nj * 16 + ln15;
#pragma unroll
      for (int r = 0; r < 4; ++r) {
        float v = acc[mi][nj][r] + biasv[nj];
        v = v > 0.f ? v : 0.f;
        size_t idx = (size_t)(row0 + r) * N + col;
        Cb[idx] = __float2bfloat16(v);
        if (Cf) Cf[idx] = v;
      }
    }
  }
}

// ---------------------------------------------------------------------------
// gemm_2c32: identical skeleton to gemm_2c but 32x32x16 MFMA.
// Frags: 4 m-frags of 32 rows (aLo=0,1; aHi=2,3), 2 n-frags of 32 cols.
// A-frag: lane reads row (lane&31), k = (lane>>5)*8..+7 of each K=16 sub
// (contiguous 8 bf16 -> one b128). Swizzled chunk = base ^ (ks<<5).
// C/D: col = lane&31, row = (r&3) + 8*(r>>2) + 4*(lane>>5)  [m74/m101].
// ---------------------------------------------------------------------------
__global__ __launch_bounds__(512, 2) void gemm_2c32(
    const __hip_bfloat16* __restrict__ A,
    const __hip_bfloat16* __restrict__ Bt,
    const float* __restrict__ bias,
    __hip_bfloat16* __restrict__ Cb,
    float* __restrict__ Cf,
    int N, int K, int nbx) {
  __shared__ char lds[131072];

  const int tid  = threadIdx.x;
  const int lane = tid & 63;
  const int wid  = tid >> 6;
  const int wm   = wid >> 2;
  const int wn   = wid & 3;

  const int nwg = gridDim.x;
  const int cpx = nwg >> 3;
  const int id  = blockIdx.x;
  const int swz = (id & 7) * cpx + (id >> 3);
  const int bm  = (swz / nbx) * 256;
  const int bn  = (swz % nbx) * 256;

  const int ln31 = lane & 31;
  const unsigned cs32 = (unsigned)((((lane >> 5) ^ (lane & 7)) << 4));

  const unsigned aoff = (unsigned)((wm * 128 + ln31) * 128) + cs32;
  const unsigned boff = 32768u + (unsigned)((wn * 64 + ln31) * 128) + cs32;

  const int nt = K >> 6;

  const __hip_bfloat16* baseA = A  + (size_t)(bm + (tid >> 3)) * K +
                                ((tid & 7) ^ ((tid >> 3) & 7)) * 8;
  const __hip_bfloat16* baseB = Bt + (size_t)(bn + (tid >> 3)) * K +
                                ((tid & 7) ^ ((tid >> 3) & 7)) * 8;
  const unsigned ldst0 = (unsigned)(wid * 1024);

  auto stage = [&](int kt, int half, int isB) {
    const __hip_bfloat16* base = isB ? baseB : baseA;
    char* dst = lds + ((kt & 1) * 65536) + (isB ? 32768 : 0) + half * 16384;
#pragma unroll
    for (int q = 0; q < 2; ++q) {
      gload16(base + (size_t)((half * 128 + q * 64) * K + kt * 64),
              dst + q * 8192 + ldst0);
    }
  };

  auto LD = [&](unsigned off) -> short8 {
    return *(const short8*)&lds[off];
  };

  f32x16 acc[4][2] = {};
  short8 aLo[2][4], aHi[2][4], b0v[4], b1v[4];

  stage(0, 0, 1); stage(0, 1, 1); stage(0, 0, 0); stage(0, 1, 0);
  if (nt > 1) {
    stage(1, 0, 1); stage(1, 1, 1); stage(1, 0, 0); stage(1, 1, 0);
    asm volatile("s_waitcnt vmcnt(8)");
  } else {
    asm volatile("s_waitcnt vmcnt(0)");
  }
  BAR();
  MEMFENCE();
#pragma unroll
  for (int mf = 0; mf < 2; ++mf)
#pragma unroll
    for (int ks = 0; ks < 4; ++ks)
      aLo[mf][ks] = LD((aoff + (unsigned)(mf * 4096)) ^ (unsigned)(ks << 5));
#pragma unroll
  for (int ks = 0; ks < 4; ++ks)
    b0v[ks] = LD(boff ^ (unsigned)(ks << 5));

  for (int t = 0; t < nt; ++t) {
    const unsigned po = (unsigned)(t & 1) * 65536u;
    const unsigned pn = po ^ 65536u;

    // ---- P1: read b1(t); Q1 = aLo x b0 ----
#pragma unroll
    for (int ks = 0; ks < 4; ++ks)
      b1v[ks] = LD((po + boff + 4096u) ^ (unsigned)(ks << 5));
    PRIO(1);
#pragma unroll
    for (int ks = 0; ks < 4; ++ks)
#pragma unroll
      for (int mf = 0; mf < 2; ++mf)
        acc[mf][0] = MFMA32(aLo[mf][ks], b0v[ks], acc[mf][0]);
    PRIO(0);

    // ---- P2: read aHi(t); Q2 = aLo x b1; BARRIER-A ----
#pragma unroll
    for (int mf = 0; mf < 2; ++mf)
#pragma unroll
      for (int ks = 0; ks < 4; ++ks)
        aHi[mf][ks] = LD((po + aoff + (unsigned)((mf + 2) * 4096)) ^ (unsigned)(ks << 5));
    PRIO(1);
#pragma unroll
    for (int ks = 0; ks < 4; ++ks)
#pragma unroll
      for (int mf = 0; mf < 2; ++mf)
        acc[mf][1] = MFMA32(aLo[mf][ks], b1v[ks], acc[mf][1]);
    PRIO(0);
    BAR();
    MEMFENCE();

    // ---- P3: Q3 = aHi x b0; stage B(t+2); publish t+1; BARRIER-B ----
    PRIO(1);
#pragma unroll
    for (int ks = 0; ks < 4; ++ks)
#pragma unroll
      for (int mf = 0; mf < 2; ++mf)
        acc[mf + 2][0] = MFMA32(aHi[mf][ks], b0v[ks], acc[mf + 2][0]);
    PRIO(0);
    if (t + 2 < nt) { stage(t + 2, 0, 1); stage(t + 2, 1, 1); }
    if (t + 1 < nt) {
      if (t + 2 < nt) asm volatile("s_waitcnt vmcnt(4)");
      else            asm volatile("s_waitcnt vmcnt(0)");
      BAR();
      MEMFENCE();
    }

    // ---- P4: read aLo,b0(t+1); Q4 = aHi x b1; stage A(t+2) ----
    if (t + 1 < nt) {
#pragma unroll
      for (int mf = 0; mf < 2; ++mf)
#pragma unroll
        for (int ks = 0; ks < 4; ++ks)
          aLo[mf][ks] = LD((pn + aoff + (unsigned)(mf * 4096)) ^ (unsigned)(ks << 5));
#pragma unroll
      for (int ks = 0; ks < 4; ++ks)
        b0v[ks] = LD((pn + boff) ^ (unsigned)(ks << 5));
    }
    PRIO(1);
#pragma unroll
    for (int ks = 0; ks < 4; ++ks)
#pragma unroll
      for (int mf = 0; mf < 2; ++mf)
        acc[mf + 2][1] = MFMA32(aHi[mf][ks], b1v[ks], acc[mf + 2][1]);
    PRIO(0);
    if (t + 2 < nt) { stage(t + 2, 0, 0); stage(t + 2, 1, 0); }
  }

  // epilogue: C/D 32x32 layout
  float biasv[2];
#pragma unroll
  for (int nf = 0; nf < 2; ++nf)
    biasv[nf] = bias[bn + wn * 64 + nf * 32 + ln31];

#pragma unroll
  for (int mf = 0; mf < 4; ++mf) {
    int rbase = bm + wm * 128 + mf * 32 + 4 * (lane >> 5);
#pragma unroll
    for (int nf = 0; nf < 2; ++nf) {
      int col = bn + wn * 64 + nf * 32 + ln31;
#pragma unroll
      for (int r = 0; r < 16; ++r) {
        int row = rbase + (r & 3) + 8 * (r >> 2);
        float v = acc[mf][nf][r] + biasv[nf];
        v = v > 0.f ? v : 0.f;
        size_t idx = (size_t)row * N + col;
        Cb[idx] = __float2bfloat16(v);
        if (Cf) Cf[idx] = v;
      }
    }
  }
}

// ---------------------------------------------------------------------------
// gemm_128: 128x256, BK=64, 8 waves 2x4 (wave tile 64x64), 2-barrier deep-
// prefetch schedule (asm reads). Loads/tile = 6; publish vmcnt(4).
// ---------------------------------------------------------------------------
__global__ __launch_bounds__(512, 2) void gemm_128(
    const __hip_bfloat16* __restrict__ A,
    const __hip_bfloat16* __restrict__ Bt,
    const float* __restrict__ bias,
    __hip_bfloat16* __restrict__ Cb,
    float* __restrict__ Cf,
    int N, int K, int nbx) {
  __shared__ char lds[98304];

  const int tid  = threadIdx.x;
  const int lane = tid & 63;
  const int wid  = tid >> 6;
  const int wm   = wid >> 2;
  const int wn   = wid & 3;

  const int nwg = gridDim.x;
  const int cpx = nwg >> 3;
  const int id  = blockIdx.x;
  const int swz = (id & 7) * cpx + (id >> 3);
  const int bm  = (swz / nbx) * 128;
  const int bn  = (swz % nbx) * 256;

  const int ln15 = lane & 15;
  const unsigned cswz = (unsigned)((((lane >> 4) ^ (lane & 7)) << 4));

  const unsigned lbase = lds_u32(lds);
  const unsigned arow0 = lbase + (unsigned)(wm * 64 + ln15) * 128u + cswz;
  const unsigned brow0 = lbase + 16384u + (unsigned)(wn * 64 + ln15) * 128u + cswz;

  const int nt = K >> 6;

  const int swc = (tid & 7) ^ ((tid >> 3) & 7);
  const __hip_bfloat16* baseA = A  + (size_t)(bm + (tid >> 3)) * K + swc * 8;
  const __hip_bfloat16* baseB = Bt + (size_t)(bn + (tid >> 3)) * K + swc * 8;
  const unsigned ldst0 = (unsigned)(tid * 16);

  auto stageA = [&](int kt, int half) {
    char* dst = lds + ((kt & 1) * 49152) + half * 8192;
    gload16(baseA + (size_t)((half * 64) * K + kt * 64), dst + ldst0);
  };
  auto stageB = [&](int kt, int half) {
    char* dst = lds + ((kt & 1) * 49152) + 16384 + half * 16384;
#pragma unroll
    for (int q = 0; q < 2; ++q) {
      gload16(baseB + (size_t)((half * 128 + q * 64) * K + kt * 64),
              dst + q * 8192 + ldst0);
    }
  };

  f32x4 acc[4][4] = {};
  short8 aLo[2][2], aHi[2][2], b0v[2][2], b1v[2][2];

  stageB(0, 0); stageB(0, 1); stageA(0, 0); stageA(0, 1);
  if (nt > 1) {
    stageB(1, 0); stageB(1, 1); stageA(1, 0); stageA(1, 1);
    asm volatile("s_waitcnt vmcnt(6)");
  } else {
    asm volatile("s_waitcnt vmcnt(0)");
  }
  BAR();
#pragma unroll
  for (int mi = 0; mi < 2; ++mi) {
    unsigned ad = arow0 + (unsigned)(mi * 2048);
    aLo[mi][0] = dsr(ad); aLo[mi][1] = dsr(ad ^ 64u);
  }

  for (int t = 0; t < nt; ++t) {
    const unsigned po = (unsigned)(t & 1) * 49152u;
    const unsigned pn = po ^ 49152u;

    asm volatile("s_waitcnt lgkmcnt(0)");
    SB0();
#pragma unroll
    for (int nj = 0; nj < 2; ++nj) b0v[nj][0] = dsr(brow0 + po + (unsigned)(nj * 2048));
#pragma unroll
    for (int nj = 0; nj < 2; ++nj) b0v[nj][1] = dsr((brow0 + po + (unsigned)(nj * 2048)) ^ 64u);
#pragma unroll
    for (int nj = 0; nj < 2; ++nj) b1v[nj][0] = dsr(brow0 + po + (unsigned)((nj + 2) * 2048));
#pragma unroll
    for (int nj = 0; nj < 2; ++nj) b1v[nj][1] = dsr((brow0 + po + (unsigned)((nj + 2) * 2048)) ^ 64u);
    asm volatile("s_waitcnt lgkmcnt(6)");
    SB0();
    PRIO(1);
#pragma unroll
    for (int mi = 0; mi < 2; ++mi)
#pragma unroll
      for (int nj = 0; nj < 2; ++nj)
        acc[mi][nj] = MFMA16(aLo[mi][0], b0v[nj][0], acc[mi][nj]);
    asm volatile("s_waitcnt lgkmcnt(4)");
    SB0();
#pragma unroll
    for (int mi = 0; mi < 2; ++mi)
#pragma unroll
      for (int nj = 0; nj < 2; ++nj)
        acc[mi][nj] = MFMA16(aLo[mi][1], b0v[nj][1], acc[mi][nj]);
    PRIO(0);

#pragma unroll
    for (int mi = 0; mi < 2; ++mi) {
      unsigned ad = arow0 + po + (unsigned)((mi + 2) * 2048);
      aHi[mi][0] = dsr(ad); aHi[mi][1] = dsr(ad ^ 64u);
    }
    asm volatile("s_waitcnt lgkmcnt(4)");
    SB0();
    PRIO(1);
#pragma unroll
    for (int kk = 0; kk < 2; ++kk)
#pragma unroll
      for (int mi = 0; mi < 2; ++mi)
#pragma unroll
        for (int nj = 0; nj < 2; ++nj)
          acc[mi][nj + 2] = MFMA16(aLo[mi][kk], b1v[nj][kk], acc[mi][nj + 2]);
    PRIO(0);
    BAR();

    asm volatile("s_waitcnt lgkmcnt(0)");
    SB0();
    PRIO(1);
#pragma unroll
    for (int kk = 0; kk < 2; ++kk)
#pragma unroll
      for (int mi = 0; mi < 2; ++mi)
#pragma unroll
        for (int nj = 0; nj < 2; ++nj)
          acc[mi + 2][nj] = MFMA16(aHi[mi][kk], b0v[nj][kk], acc[mi + 2][nj]);
    PRIO(0);
    if (t + 2 < nt) { stageB(t + 2, 0); stageB(t + 2, 1); }
    if (t + 1 < nt) {
      if (t + 2 < nt) asm volatile("s_waitcnt vmcnt(4)");
      else            asm volatile("s_waitcnt vmcnt(0)");
      BAR();
    }

    if (t + 1 < nt) {
#pragma unroll
      for (int mi = 0; mi < 2; ++mi) {
        unsigned ad = arow0 + pn + (unsigned)(mi * 2048);
        aLo[mi][0] = dsr(ad); aLo[mi][1] = dsr(ad ^ 64u);
      }
    }
    SB0();
    PRIO(1);
#pragma unroll
    for (int kk = 0; kk < 2; ++kk)
#pragma unroll
      for (int mi = 0; mi < 2; ++mi)
#pragma unroll
        for (int nj = 0; nj < 2; ++nj)
          acc[mi + 2][nj + 2] = MFMA16(aHi[mi][kk], b1v[nj][kk], acc[mi + 2][nj + 2]);
    PRIO(0);
    if (t + 2 < nt) { stageA(t + 2, 0); stageA(t + 2, 1); }
  }

  float biasv[4];
#pragma unroll
  for (int nj = 0; nj < 4; ++nj)
    biasv[nj] = bias[bn + wn * 64 + nj * 16 + ln15];

#pragma unroll
  for (int mi = 0; mi < 4; ++mi) {
    int row0 = bm + wm * 64 + mi * 16 + (lane >> 4) * 4;
#pragma unroll
    for (int nj = 0; nj < 4; ++nj) {
      int col = bn + wn * 64 + nj * 16 + ln15;
#pragma unroll
      for (int r = 0; r < 4; ++r) {
        float v = acc[mi][nj][r] + biasv[nj];
        v = v > 0.f ? v : 0.f;
        size_t idx = (size_t)(row0 + r) * N + col;
        Cb[idx] = __float2bfloat16(v);
        if (Cf) Cf[idx] = v;
      }
    }
  }
}

// ---------------------------------------------------------------------------
// gemm_l5h: L5 (128x256, K=512, block owns all 256 cols) + fused domain head.
// ---------------------------------------------------------------------------
__global__ __launch_bounds__(512, 2) void gemm_l5h(
    const __hip_bfloat16* __restrict__ A,
    const __hip_bfloat16* __restrict__ Bt,
    const float* __restrict__ bias,
    float* __restrict__ Df,
    const float* __restrict__ wide,
    const int* __restrict__ dom,
    const float* __restrict__ Wh,
    const float* __restrict__ bh,
    float* __restrict__ outp,
    int K) {
  __shared__ char lds[98304];

  const int tid  = threadIdx.x;
  const int lane = tid & 63;
  const int wid  = tid >> 6;
  const int wm   = wid >> 2;
  const int wn   = wid & 3;

  const int nwg = gridDim.x;
  const int cpx = nwg >> 3;
  const int id  = blockIdx.x;
  const int swz = (id & 7) * cpx + (id >> 3);
  const int bm  = swz * 128;

  const int ln15 = lane & 15;
  const unsigned cswz = (unsigned)((((lane >> 4) ^ (lane & 7)) << 4));

  const unsigned lbase = lds_u32(lds);
  const unsigned arow0 = lbase + (unsigned)(wm * 64 + ln15) * 128u + cswz;
  const unsigned brow0 = lbase + 16384u + (unsigned)(wn * 64 + ln15) * 128u + cswz;

  const int nt = K >> 6;

  const int swc = (tid & 7) ^ ((tid >> 3) & 7);
  const __hip_bfloat16* baseA = A  + (size_t)(bm + (tid >> 3)) * K + swc * 8;
  const __hip_bfloat16* baseB = Bt + (size_t)(tid >> 3) * K + swc * 8;
  const unsigned ldst0 = (unsigned)(tid * 16);

  auto stageA = [&](int kt, int half) {
    char* dst = lds + ((kt & 1) * 49152) + half * 8192;
    gload16(baseA + (size_t)((half * 64) * K + kt * 64), dst + ldst0);
  };
  auto stageB = [&](int kt, int half) {
    char* dst = lds + ((kt & 1) * 49152) + 16384 + half * 16384;
#pragma unroll
    for (int q = 0; q < 2; ++q) {
      gload16(baseB + (size_t)((half * 128 + q * 64) * K + kt * 64),
              dst + q * 8192 + ldst0);
    }
  };

  f32x4 acc[4][4] = {};
  short8 aLo[2][2], aHi[2][2], b0v[2][2], b1v[2][2];

  stageB(0, 0); stageB(0, 1); stageA(0, 0); stageA(0, 1);
  if (nt > 1) {
    stageB(1, 0); stageB(1, 1); stageA(1, 0); stageA(1, 1);
    asm volatile("s_waitcnt vmcnt(6)");
  } else {
    asm volatile("s_waitcnt vmcnt(0)");
  }
  BAR();
#pragma unroll
  for (int mi = 0; mi < 2; ++mi) {
    unsigned ad = arow0 + (unsigned)(mi * 2048);
    aLo[mi][0] = dsr(ad); aLo[mi][1] = dsr(ad ^ 64u);
  }

  for (int t = 0; t < nt; ++t) {
    const unsigned po = (unsigned)(t & 1) * 49152u;
    const unsigned pn = po ^ 49152u;

    asm volatile("s_waitcnt lgkmcnt(0)");
    SB0();
#pragma unroll
    for (int nj = 0; nj < 2; ++nj) b0v[nj][0] = dsr(brow0 + po + (unsigned)(nj * 2048));
#pragma unroll
    for (int nj = 0; nj < 2; ++nj) b0v[nj][1] = dsr((brow0 + po + (unsigned)(nj * 2048)) ^ 64u);
#pragma unroll
    for (int nj = 0; nj < 2; ++nj) b1v[nj][0] = dsr(brow0 + po + (unsigned)((nj + 2) * 2048));
#pragma unroll
    for (int nj = 0; nj < 2; ++nj) b1v[nj][1] = dsr((brow0 + po + (unsigned)((nj + 2) * 2048)) ^ 64u);
    asm volatile("s_waitcnt lgkmcnt(6)");
    SB0();
    PRIO(1);
#pragma unroll
    for (int mi = 0; mi < 2; ++mi)
#pragma unroll
      for (int nj = 0; nj < 2; ++nj)
        acc[mi][nj] = MFMA16(aLo[mi][0], b0v[nj][0], acc[mi][nj]);
    asm volatile("s_waitcnt lgkmcnt(4)");
    SB0();
#pragma unroll
    for (int mi = 0; mi < 2; ++mi)
#pragma unroll
      for (int nj = 0; nj < 2; ++nj)
        acc[mi][nj] = MFMA16(aLo[mi][1], b0v[nj][1], acc[mi][nj]);
    PRIO(0);

#pragma unroll
    for (int mi = 0; mi < 2; ++mi) {
      unsigned ad = arow0 + po + (unsigned)((mi + 2) * 2048);
      aHi[mi][0] = dsr(ad); aHi[mi][1] = dsr(ad ^ 64u);
    }
    asm volatile("s_waitcnt lgkmcnt(4)");
    SB0();
    PRIO(1);
#pragma unroll
    for (int kk = 0; kk < 2; ++kk)
#pragma unroll
      for (int mi = 0; mi < 2; ++mi)
#pragma unroll
        for (int nj = 0; nj < 2; ++nj)
          acc[mi][nj + 2] = MFMA16(aLo[mi][kk], b1v[nj][kk], acc[mi][nj + 2]);
    PRIO(0);
    BAR();

    asm volatile("s_waitcnt lgkmcnt(0)");
    SB0();
    PRIO(1);
#pragma unroll
    for (int kk = 0; kk < 2; ++kk)
#pragma unroll
      for (int mi = 0; mi < 2; ++mi)
#pragma unroll
        for (int nj = 0; nj < 2; ++nj)
          acc[mi + 2][nj] = MFMA16(aHi[mi][kk], b0v[nj][kk], acc[mi + 2][nj]);
    PRIO(0);
    if (t + 2 < nt) { stageB(t + 2, 0); stageB(t + 2, 1); }
    if (t + 1 < nt) {
      if (t + 2 < nt) asm volatile("s_waitcnt vmcnt(4)");
      else            asm volatile("s_waitcnt vmcnt(0)");
      BAR();
    }

    if (t + 1 < nt) {
#pragma unroll
      for (int mi = 0; mi < 2; ++mi) {
        unsigned ad = arow0 + pn + (unsigned)(mi * 2048);
        aLo[mi][0] = dsr(ad); aLo[mi][1] = dsr(ad ^ 64u);
      }
    }
    SB0();
    PRIO(1);
#pragma unroll
    for (int kk = 0; kk < 2; ++kk)
#pragma unroll
      for (int mi = 0; mi < 2; ++mi)
#pragma unroll
        for (int nj = 0; nj < 2; ++nj)
          acc[mi + 2][nj + 2] = MFMA16(aHi[mi][kk], b1v[nj][kk], acc[mi + 2][nj + 2]);
    PRIO(0);
    if (t + 2 < nt) { stageA(t + 2, 0); stageA(t + 2, 1); }
  }

  // ---- fused epilogue ----
  BAR();
  MEMFENCE();
  unsigned short* ldsD = (unsigned short*)lds;          // [128][264] bf16
  float* ldsH = (float*)(lds + 128 * 264 * 2);          // [128][4] f32

  float biasv[4];
#pragma unroll
  for (int nj = 0; nj < 4; ++nj)
    biasv[nj] = bias[wn * 64 + nj * 16 + ln15];

#pragma unroll
  for (int mi = 0; mi < 4; ++mi) {
    int lrow0 = wm * 64 + mi * 16 + (lane >> 4) * 4;
#pragma unroll
    for (int nj = 0; nj < 4; ++nj) {
      int col = wn * 64 + nj * 16 + ln15;
#pragma unroll
      for (int r = 0; r < 4; ++r) {
        float v = acc[mi][nj][r] + biasv[nj];
        v = v > 0.f ? v : 0.f;
        Df[(size_t)(bm + lrow0 + r) * 256 + col] = v;
        ldsD[(lrow0 + r) * 264 + col] = f2bf_bits(v);
      }
    }
  }

  const int erow = tid >> 2;
  const int eq   = tid & 3;
  float s = 0.f;
  {
    const f32x4* wp = (const f32x4*)(wide + (size_t)(bm + erow) * 256 + eq * 64);
#pragma unroll
    for (int j = 0; j < 16; ++j) {
      f32x4 w = wp[j];
      s += w[0] + w[1] + w[2] + w[3];
    }
  }
  BAR();
  MEMFENCE();

  const int dm = dom[bm + erow];
  float h = 0.f;
  {
    const f32x4* hp = (const f32x4*)(Wh + (size_t)dm * 256 + eq * 64);
    const short8* dp = (const short8*)(ldsD + erow * 264 + eq * 64);
#pragma unroll
    for (int j = 0; j < 8; ++j) {
      short8 d8 = dp[j];
      f32x4 h0 = hp[j * 2], h1 = hp[j * 2 + 1];
      h += bf_bits2f((unsigned short)d8[0]) * h0[0] +
           bf_bits2f((unsigned short)d8[1]) * h0[1] +
           bf_bits2f((unsigned short)d8[2]) * h0[2] +
           bf_bits2f((unsigned short)d8[3]) * h0[3] +
           bf_bits2f((unsigned short)d8[4]) * h1[0] +
           bf_bits2f((unsigned short)d8[5]) * h1[1] +
           bf_bits2f((unsigned short)d8[6]) * h1[2] +
           bf_bits2f((unsigned short)d8[7]) * h1[3];
    }
  }
  ldsH[erow * 4 + eq] = s + h;
  BAR();
  MEMFENCE();

  if (tid < 128) {
    float val = ldsH[tid * 4] + ldsH[tid * 4 + 1] +
                ldsH[tid * 4 + 2] + ldsH[tid * 4 + 3];
    int dmr = dom[bm + tid];
    float x = val + bh[dmr];
    outp[bm + tid] = 1.f / (1.f + __expf(-x));
  }
}

// ---------------------------------------------------------------------------
extern "C" void kernel_launch(void* const* d_in, const int* in_sizes, int n_in,
                              void* d_out, int out_size, void* d_ws, size_t ws_size,
                              hipStream_t stream) {
  const float* wide = (const float*)d_in[0];
  const float* deep = (const float*)d_in[1];
  const int*   dom  = (const int*)d_in[2];
  const float* W1  = (const float*)d_in[3];
  const float* b1  = (const float*)d_in[4];
  const float* W2  = (const float*)d_in[5];
  const float* b2  = (const float*)d_in[6];
  const float* W3  = (const float*)d_in[7];
  const float* b3  = (const float*)d_in[8];
  const float* Wd1 = (const float*)d_in[9];
  const float* bd1 = (const float*)d_in[10];
  const float* Wd2 = (const float*)d_in[11];
  const float* bd2 = (const float*)d_in[12];
  const float* Wh  = (const float*)d_in[13];
  const float* bh  = (const float*)d_in[14];
  float* out = (float*)d_out;

  const int B = 16384;
  char* ws = (char*)d_ws;
  __hip_bfloat16* buf0 = (__hip_bfloat16*)ws;
  __hip_bfloat16* buf1 = (__hip_bfloat16*)(ws + 33554432ull);
  __hip_bfloat16* W1t  = (__hip_bfloat16*)(ws + 100663296ull);
  __hip_bfloat16* W2t  = W1t + 2048 * 1024;
  __hip_bfloat16* W3t  = W2t + 1024 * 2048;
  __hip_bfloat16* Wd1t = W3t + 512 * 1024;
  __hip_bfloat16* Wd2t = Wd1t + 512 * 512;

  // fused preprocessing: deep->bf16 + 5 weight transposes
  prep<<<dim3(8192 + 1248), 256, 0, stream>>>(
      deep, (unsigned short*)buf0, W1, W1t, W2, W2t, W3, W3t, Wd1, Wd1t, Wd2, Wd2t);

  float* shared_out = out + B;
  float* d_out_f    = out + B + (size_t)B * 512;

  // L1: [B,1024]x[1024,2048] -> H1 (buf1)   [16x16x32 control]
  gemm_2c<<<dim3((2048 / 256) * (B / 256)), 512, 0, stream>>>(
      buf0, W1t, b1, buf1, nullptr, 2048, 1024, 2048 / 256);
  // L2: [B,2048]x[2048,1024] -> H2 (buf0)   [32x32x16 variant]
  gemm_2c32<<<dim3((1024 / 256) * (B / 256)), 512, 0, stream>>>(
      buf1, W2t, b2, buf0, nullptr, 1024, 2048, 1024 / 256);
  // L3: [B,1024]x[1024,512] -> S (buf1 bf16 + fp32 out)
  gemm_128<<<dim3((B / 128) * (512 / 256)), 512, 0, stream>>>(
      buf0, W3t, b3, buf1, shared_out, 512, 1024, 512 / 256);
  // L4: [B,512]x[512,512] -> T1 (buf0)
  gemm_128<<<dim3((B / 128) * (512 / 256)), 512, 0, stream>>>(
      buf1, Wd1t, bd1, buf0, nullptr, 512, 512, 512 / 256);
  // L5 + head: [B,512]x[512,256] -> d (fp32 out) + out
  gemm_l5h<<<dim3(B / 128), 512, 0, stream>>>(
      buf0, Wd2t, bd2, d_out_f, wide, dom, Wh, bh, out, 512);
}

// Round 11
// 200.672 us; speedup vs baseline: 3.3260x; 1.0869x over previous
//
#include <hip/hip_runtime.h>
#include <hip/hip_bf16.h>

// ---------------------------------------------------------------------------
// Wide&Deep forward.
// prep: fused deep-convert + 5 weight transposes.
// L1/L2: gemm_2c (256x256, 16x16x32, 2-barrier deep-prefetch schedule).
// tower: fused L3->L4->L5->head megakernel, 64 rows/block, 256 blocks.
//   S and T1 live in LDS between layers (XOR-chunk layout, <=2-way banks).
// ---------------------------------------------------------------------------

typedef __attribute__((ext_vector_type(8))) short short8;
typedef __attribute__((ext_vector_type(4))) float f32x4;

static __device__ __forceinline__ unsigned short f2bf_bits(float x) {
  __hip_bfloat16 h = __float2bfloat16(x);
  return __builtin_bit_cast(unsigned short, h);
}
static __device__ __forceinline__ float bf_bits2f(unsigned short u) {
  __hip_bfloat16 h = __builtin_bit_cast(__hip_bfloat16, u);
  return __bfloat162float(h);
}

static __device__ __forceinline__ void gload16(const void* g, void* l) {
  __builtin_amdgcn_global_load_lds(
      (const __attribute__((address_space(1))) void*)g,
      (__attribute__((address_space(3))) void*)l, 16, 0, 0);
}

#define MFMA16(a, b, c) __builtin_amdgcn_mfma_f32_16x16x32_bf16((a), (b), (c), 0, 0, 0)
#define SB0() __builtin_amdgcn_sched_barrier(0)
#define PRIO(x) __builtin_amdgcn_s_setprio(x)
#define BAR() __builtin_amdgcn_s_barrier()
#define MEMFENCE() asm volatile("" ::: "memory")

// ---------------------------------------------------------------------------
// prep: blocks [0,8192): deep f32->bf16; [8192,9440): weight transposes.
// ---------------------------------------------------------------------------
__global__ __launch_bounds__(256) void prep(
    const float* __restrict__ deep, unsigned short* __restrict__ deepb,
    const float* __restrict__ W1, __hip_bfloat16* __restrict__ W1t,
    const float* __restrict__ W2, __hip_bfloat16* __restrict__ W2t,
    const float* __restrict__ W3, __hip_bfloat16* __restrict__ W3t,
    const float* __restrict__ Wd1, __hip_bfloat16* __restrict__ Wd1t,
    const float* __restrict__ Wd2, __hip_bfloat16* __restrict__ Wd2t) {
  __shared__ float tile[64][65];
  int blk = blockIdx.x;
  if (blk < 8192) {
    int i = blk * 256 + threadIdx.x;
    const f32x4* p = (const f32x4*)deep + (size_t)i * 2;
    f32x4 a = p[0], b = p[1];
    short8 o;
    o[0] = (short)f2bf_bits(a[0]); o[1] = (short)f2bf_bits(a[1]);
    o[2] = (short)f2bf_bits(a[2]); o[3] = (short)f2bf_bits(a[3]);
    o[4] = (short)f2bf_bits(b[0]); o[5] = (short)f2bf_bits(b[1]);
    o[6] = (short)f2bf_bits(b[2]); o[7] = (short)f2bf_bits(b[3]);
    *(short8*)(deepb + (size_t)i * 8) = o;
    return;
  }
  blk -= 8192;
  const float* W; __hip_bfloat16* Wt; int K, N;
  if (blk < 512)       {             W = W1;  Wt = W1t;  K = 1024; N = 2048; }
  else if (blk < 1024) { blk -= 512;  W = W2;  Wt = W2t;  K = 2048; N = 1024; }
  else if (blk < 1152) { blk -= 1024; W = W3;  Wt = W3t;  K = 1024; N = 512; }
  else if (blk < 1216) { blk -= 1152; W = Wd1; Wt = Wd1t; K = 512;  N = 512; }
  else                 { blk -= 1216; W = Wd2; Wt = Wd2t; K = 512;  N = 256; }
  const int ntx = N >> 6;
  const int k0 = (blk / ntx) * 64;
  const int n0 = (blk % ntx) * 64;
  const int t  = threadIdx.x;
  const int tn = t & 63;
  const int t4 = t >> 6;
#pragma unroll
  for (int p = 0; p < 16; ++p) {
    int kl = p * 4 + t4;
    tile[kl][tn] = W[(size_t)(k0 + kl) * N + (n0 + tn)];
  }
  __syncthreads();
#pragma unroll
  for (int p = 0; p < 16; ++p) {
    int nl = p * 4 + t4;
    Wt[(size_t)(n0 + nl) * K + (k0 + tn)] = __float2bfloat16(tile[tn][nl]);
  }
}

// ---------------------------------------------------------------------------
// gemm_2c: 256x256, BK=64, 8 waves 2x4, 16x16x32 MFMA, R9 schedule.
// ---------------------------------------------------------------------------
__global__ __launch_bounds__(512, 2) void gemm_2c(
    const __hip_bfloat16* __restrict__ A,
    const __hip_bfloat16* __restrict__ Bt,
    const float* __restrict__ bias,
    __hip_bfloat16* __restrict__ Cb,
    float* __restrict__ Cf,
    int N, int K, int nbx) {
  __shared__ char lds[131072];

  const int tid  = threadIdx.x;
  const int lane = tid & 63;
  const int wid  = tid >> 6;
  const int wm   = wid >> 2;
  const int wn   = wid & 3;

  const int nwg = gridDim.x;
  const int cpx = nwg >> 3;
  const int id  = blockIdx.x;
  const int swz = (id & 7) * cpx + (id >> 3);
  const int bm  = (swz / nbx) * 256;
  const int bn  = (swz % nbx) * 256;

  const int ln15 = lane & 15;
  const unsigned aoff = (unsigned)((wm * 128 + ln15) * 128) +
                        (unsigned)((((lane >> 4) ^ (lane & 7)) << 4));
  const unsigned boff = 32768u + (unsigned)((wn * 64 + ln15) * 128) +
                        (unsigned)((((lane >> 4) ^ (lane & 7)) << 4));

  const int nt = K >> 6;

  const __hip_bfloat16* baseA = A  + (size_t)(bm + (tid >> 3)) * K +
                                ((tid & 7) ^ ((tid >> 3) & 7)) * 8;
  const __hip_bfloat16* baseB = Bt + (size_t)(bn + (tid >> 3)) * K +
                                ((tid & 7) ^ ((tid >> 3) & 7)) * 8;
  const unsigned ldst0 = (unsigned)(wid * 1024);

  auto stage = [&](int kt, int half, int isB) {
    const __hip_bfloat16* base = isB ? baseB : baseA;
    char* dst = lds + ((kt & 1) * 65536) + (isB ? 32768 : 0) + half * 16384;
#pragma unroll
    for (int q = 0; q < 2; ++q) {
      gload16(base + (size_t)((half * 128 + q * 64) * K + kt * 64),
              dst + q * 8192 + ldst0);
    }
  };

  auto LD = [&](unsigned off) -> short8 {
    return *(const short8*)&lds[off];
  };

  f32x4 acc[8][4] = {};
  short8 aLo[4][2], aHi[4][2], b0v[2][2], b1v[2][2];

  stage(0, 0, 1); stage(0, 1, 1); stage(0, 0, 0); stage(0, 1, 0);
  if (nt > 1) {
    stage(1, 0, 1); stage(1, 1, 1); stage(1, 0, 0); stage(1, 1, 0);
    asm volatile("s_waitcnt vmcnt(8)");
  } else {
    asm volatile("s_waitcnt vmcnt(0)");
  }
  BAR();
  MEMFENCE();
#pragma unroll
  for (int mi = 0; mi < 4; ++mi)
#pragma unroll
    for (int kk = 0; kk < 2; ++kk)
      aLo[mi][kk] = LD((aoff + (unsigned)(mi * 2048)) ^ (unsigned)(kk << 6));
#pragma unroll
  for (int nj = 0; nj < 2; ++nj)
#pragma unroll
    for (int kk = 0; kk < 2; ++kk)
      b0v[nj][kk] = LD((boff + (unsigned)(nj * 2048)) ^ (unsigned)(kk << 6));

  for (int t = 0; t < nt; ++t) {
    const unsigned po = (unsigned)(t & 1) * 65536u;
    const unsigned pn = po ^ 65536u;

    // ---- P1 ----
#pragma unroll
    for (int nj = 0; nj < 2; ++nj)
#pragma unroll
      for (int kk = 0; kk < 2; ++kk)
        b1v[nj][kk] = LD((po + boff + (unsigned)((nj + 2) * 2048)) ^ (unsigned)(kk << 6));
    PRIO(1);
#pragma unroll
    for (int kk = 0; kk < 2; ++kk)
#pragma unroll
      for (int mi = 0; mi < 4; ++mi)
#pragma unroll
        for (int nj = 0; nj < 2; ++nj)
          acc[mi][nj] = MFMA16(aLo[mi][kk], b0v[nj][kk], acc[mi][nj]);
    PRIO(0);

    // ---- P2 ----
#pragma unroll
    for (int mi = 0; mi < 4; ++mi)
#pragma unroll
      for (int kk = 0; kk < 2; ++kk)
        aHi[mi][kk] = LD((po + aoff + (unsigned)((mi + 4) * 2048)) ^ (unsigned)(kk << 6));
    PRIO(1);
#pragma unroll
    for (int kk = 0; kk < 2; ++kk)
#pragma unroll
      for (int mi = 0; mi < 4; ++mi)
#pragma unroll
        for (int nj = 0; nj < 2; ++nj)
          acc[mi][nj + 2] = MFMA16(aLo[mi][kk], b1v[nj][kk], acc[mi][nj + 2]);
    PRIO(0);
    BAR();
    MEMFENCE();

    // ---- P3 ----
    PRIO(1);
#pragma unroll
    for (int kk = 0; kk < 2; ++kk)
#pragma unroll
      for (int mi = 0; mi < 4; ++mi)
#pragma unroll
        for (int nj = 0; nj < 2; ++nj)
          acc[mi + 4][nj] = MFMA16(aHi[mi][kk], b0v[nj][kk], acc[mi + 4][nj]);
    PRIO(0);
    if (t + 2 < nt) { stage(t + 2, 0, 1); stage(t + 2, 1, 1); }
    if (t + 1 < nt) {
      if (t + 2 < nt) asm volatile("s_waitcnt vmcnt(4)");
      else            asm volatile("s_waitcnt vmcnt(0)");
      BAR();
      MEMFENCE();
    }

    // ---- P4 ----
    if (t + 1 < nt) {
#pragma unroll
      for (int mi = 0; mi < 4; ++mi)
#pragma unroll
        for (int kk = 0; kk < 2; ++kk)
          aLo[mi][kk] = LD((pn + aoff + (unsigned)(mi * 2048)) ^ (unsigned)(kk << 6));
#pragma unroll
      for (int nj = 0; nj < 2; ++nj)
#pragma unroll
        for (int kk = 0; kk < 2; ++kk)
          b0v[nj][kk] = LD((pn + boff + (unsigned)(nj * 2048)) ^ (unsigned)(kk << 6));
    }
    PRIO(1);
#pragma unroll
    for (int kk = 0; kk < 2; ++kk)
#pragma unroll
      for (int mi = 0; mi < 4; ++mi)
#pragma unroll
        for (int nj = 0; nj < 2; ++nj)
          acc[mi + 4][nj + 2] = MFMA16(aHi[mi][kk], b1v[nj][kk], acc[mi + 4][nj + 2]);
    PRIO(0);
    if (t + 2 < nt) { stage(t + 2, 0, 0); stage(t + 2, 1, 0); }
  }

  float biasv[4];
#pragma unroll
  for (int nj = 0; nj < 4; ++nj)
    biasv[nj] = bias[bn + wn * 64 + nj * 16 + ln15];

#pragma unroll
  for (int mi = 0; mi < 8; ++mi) {
    int row0 = bm + wm * 128 + mi * 16 + (lane >> 4) * 4;
#pragma unroll
    for (int nj = 0; nj < 4; ++nj) {
      int col = bn + wn * 64 + nj * 16 + ln15;
#pragma unroll
      for (int r = 0; r < 4; ++r) {
        float v = acc[mi][nj][r] + biasv[nj];
        v = v > 0.f ? v : 0.f;
        size_t idx = (size_t)(row0 + r) * N + col;
        Cb[idx] = __float2bfloat16(v);
        if (Cf) Cf[idx] = v;
      }
    }
  }
}

// ---------------------------------------------------------------------------
// tower: fused L3 -> L4 -> L5 -> head. 64 rows/block, 256 blocks, 8 waves.
// LDS map (139264 B total):
//   [0,65536):       S/T1 region, [64 rows][1024 B], chunk c stored at
//                    byte r*1024 + ((c ^ (r&7))<<4)    (c = k>>3)
//   [65536,73728):   L3 A dbuf (2 x 4096)      | later: Dlds [64][264] bf16
//   [73728,139264):  L3/L4 B dbuf (2 x 32768)  | L5 B dbuf (2 x 16384)
//   [100352,102400): ldsH head partials (after L5 reads retired)
// Staged K-tiles (BK=32): [rows][64 B], chunk f-XOR f(r) = (r>>1)&3
// (pre-swizzled global source, linear LDS dest; <=2-way banks, audited).
// Staging loop (2 barriers/tile): stage(t+1); vmcnt(keep t+1); BAR(publish t);
// reads; MFMA; BAR(reads retired -> next overwrite safe).
// ---------------------------------------------------------------------------
__global__ __launch_bounds__(512, 2) void tower(
    const __hip_bfloat16* __restrict__ H2,
    const __hip_bfloat16* __restrict__ W3t, const float* __restrict__ b3,
    const __hip_bfloat16* __restrict__ Wd1t, const float* __restrict__ bd1,
    const __hip_bfloat16* __restrict__ Wd2t, const float* __restrict__ bd2,
    float* __restrict__ Sf, float* __restrict__ Df,
    const float* __restrict__ wide, const int* __restrict__ dom,
    const float* __restrict__ Wh, const float* __restrict__ bh,
    float* __restrict__ outp) {
  __shared__ char lds[139264];
  const int tid  = threadIdx.x;
  const int lane = tid & 63;
  const int wid  = tid >> 6;
  const int ln15 = lane & 15;
  const int kq   = lane >> 4;              // 0..3 : 16B k-chunk of frag

  const int id  = blockIdx.x;
  const int swz = (id & 7) * 32 + (id >> 3);   // 256 % 8 == 0, bijective
  const int bm  = swz * 64;

  // frag-read chunk select: (kq ^ f(row)) with f(row)=(row>>1)&3 = (ln15>>1)&3
  const unsigned csel = (unsigned)(((unsigned)kq ^ (unsigned)((ln15 >> 1) & 3)) << 4);
  // staging pre-swizzle: thread's row = tid>>2, chunk = tid&3
  const int sc   = (tid & 3) ^ ((tid >> 3) & 3);
  const int srow = tid >> 2;               // 0..127

  auto LD = [&](unsigned off) -> short8 { return *(const short8*)&lds[off]; };

  // ---------------- L3: S = relu(H2 @ W3t^T + b3), K=1024, 32 tiles --------
  auto stage3 = [&](int kt) {
    int half = kt & 1;
#pragma unroll
    for (int q = 0; q < 4; ++q)
      gload16(W3t + (size_t)(q * 128 + srow) * 1024 + kt * 32 + sc * 8,
              lds + 73728 + half * 32768 + q * 8192 + tid * 16);
    if (tid < 256)
      gload16(H2 + (size_t)(bm + srow) * 1024 + kt * 32 + sc * 8,
              lds + 65536 + half * 4096 + tid * 16);
  };

  f32x4 acc3[4][4] = {};
  stage3(0);
  for (int t = 0; t < 32; ++t) {
    if (t + 1 < 32) {
      stage3(t + 1);
      if (wid < 4) asm volatile("s_waitcnt vmcnt(5)");
      else         asm volatile("s_waitcnt vmcnt(4)");
    } else {
      asm volatile("s_waitcnt vmcnt(0)");
    }
    BAR(); MEMFENCE();
    const unsigned pa = 65536u + (unsigned)((t & 1) * 4096);
    const unsigned pb = 73728u + (unsigned)((t & 1) * 32768);
    short8 aF[4], bF[4];
#pragma unroll
    for (int mi = 0; mi < 4; ++mi)
      aF[mi] = LD(pa + (unsigned)((mi * 16 + ln15) * 64) + csel);
#pragma unroll
    for (int nj = 0; nj < 4; ++nj)
      bF[nj] = LD(pb + (unsigned)((wid * 64 + nj * 16 + ln15) * 64) + csel);
    PRIO(1);
#pragma unroll
    for (int mi = 0; mi < 4; ++mi)
#pragma unroll
      for (int nj = 0; nj < 4; ++nj)
        acc3[mi][nj] = MFMA16(aF[mi], bF[nj], acc3[mi][nj]);
    PRIO(0);
    BAR(); MEMFENCE();
  }

  // S epilogue: fp32 -> global, bf16 -> region0 (XOR-chunk layout)
  {
    float bv[4];
#pragma unroll
    for (int nj = 0; nj < 4; ++nj) bv[nj] = b3[wid * 64 + nj * 16 + ln15];
#pragma unroll
    for (int mi = 0; mi < 4; ++mi) {
      int lrow = mi * 16 + kq * 4;
#pragma unroll
      for (int nj = 0; nj < 4; ++nj) {
        int col = wid * 64 + nj * 16 + ln15;
#pragma unroll
        for (int r = 0; r < 4; ++r) {
          float v = acc3[mi][nj][r] + bv[nj];
          v = v > 0.f ? v : 0.f;
          Sf[(size_t)(bm + lrow + r) * 512 + col] = v;
          int rr = lrow + r;
          *(unsigned short*)&lds[rr * 1024 + (((col >> 3) ^ (rr & 7)) << 4) +
                                 (col & 7) * 2] = f2bf_bits(v);
        }
      }
    }
  }

  // ---------------- L4: T1 = relu(S @ Wd1t^T + bd1), K=512, 16 tiles -------
  auto stage4 = [&](int kt) {
    int half = kt & 1;
#pragma unroll
    for (int q = 0; q < 4; ++q)
      gload16(Wd1t + (size_t)(q * 128 + srow) * 512 + kt * 32 + sc * 8,
              lds + 73728 + half * 32768 + q * 8192 + tid * 16);
  };
  stage4(0);                          // into B half0 (L3's half0 reads retired)
  asm volatile("s_waitcnt lgkmcnt(0)");
  BAR(); MEMFENCE();                  // publish S to all waves

  f32x4 acc4[4][4] = {};
  for (int t = 0; t < 16; ++t) {
    if (t + 1 < 16) { stage4(t + 1); asm volatile("s_waitcnt vmcnt(4)"); }
    else            { asm volatile("s_waitcnt vmcnt(0)"); }
    BAR(); MEMFENCE();
    const unsigned pb = 73728u + (unsigned)((t & 1) * 32768);
    short8 aF[4], bF[4];
#pragma unroll
    for (int mi = 0; mi < 4; ++mi) {
      int rr = mi * 16 + ln15;
      aF[mi] = LD((unsigned)(rr * 1024) +
                  (unsigned)((((t * 4 + kq) ^ (rr & 7)) << 4)));
    }
#pragma unroll
    for (int nj = 0; nj < 4; ++nj)
      bF[nj] = LD(pb + (unsigned)((wid * 64 + nj * 16 + ln15) * 64) + csel);
    PRIO(1);
#pragma unroll
    for (int mi = 0; mi < 4; ++mi)
#pragma unroll
      for (int nj = 0; nj < 4; ++nj)
        acc4[mi][nj] = MFMA16(aF[mi], bF[nj], acc4[mi][nj]);
    PRIO(0);
    BAR(); MEMFENCE();
  }

  // T1 epilogue: bf16 -> region0 (overwrites S; reads certified retired)
  {
    float bv[4];
#pragma unroll
    for (int nj = 0; nj < 4; ++nj) bv[nj] = bd1[wid * 64 + nj * 16 + ln15];
#pragma unroll
    for (int mi = 0; mi < 4; ++mi) {
      int lrow = mi * 16 + kq * 4;
#pragma unroll
      for (int nj = 0; nj < 4; ++nj) {
        int col = wid * 64 + nj * 16 + ln15;
#pragma unroll
        for (int r = 0; r < 4; ++r) {
          float v = acc4[mi][nj][r] + bv[nj];
          v = v > 0.f ? v : 0.f;
          int rr = lrow + r;
          *(unsigned short*)&lds[rr * 1024 + (((col >> 3) ^ (rr & 7)) << 4) +
                                 (col & 7) * 2] = f2bf_bits(v);
        }
      }
    }
  }

  // ---------------- L5: D = relu(T1 @ Wd2t^T + bd2), K=512, 16 tiles -------
  auto stage5 = [&](int kt) {
    int half = kt & 1;
#pragma unroll
    for (int q = 0; q < 2; ++q)
      gload16(Wd2t + (size_t)(q * 128 + srow) * 512 + kt * 32 + sc * 8,
              lds + 73728 + half * 16384 + q * 8192 + tid * 16);
  };
  stage5(0);                          // B half0 region: L4 half0 reads retired
  asm volatile("s_waitcnt lgkmcnt(0)");
  BAR(); MEMFENCE();                  // publish T1

  f32x4 acc5[4][2] = {};
  for (int t = 0; t < 16; ++t) {
    if (t + 1 < 16) { stage5(t + 1); asm volatile("s_waitcnt vmcnt(2)"); }
    else            { asm volatile("s_waitcnt vmcnt(0)"); }
    BAR(); MEMFENCE();
    const unsigned pb = 73728u + (unsigned)((t & 1) * 16384);
    short8 aF[4], bF[2];
#pragma unroll
    for (int mi = 0; mi < 4; ++mi) {
      int rr = mi * 16 + ln15;
      aF[mi] = LD((unsigned)(rr * 1024) +
                  (unsigned)((((t * 4 + kq) ^ (rr & 7)) << 4)));
    }
#pragma unroll
    for (int nj = 0; nj < 2; ++nj)
      bF[nj] = LD(pb + (unsigned)((wid * 32 + nj * 16 + ln15) * 64) + csel);
    PRIO(1);
#pragma unroll
    for (int mi = 0; mi < 4; ++mi)
#pragma unroll
      for (int nj = 0; nj < 2; ++nj)
        acc5[mi][nj] = MFMA16(aF[mi], bF[nj], acc5[mi][nj]);
    PRIO(0);
    BAR(); MEMFENCE();
  }

  // D epilogue: fp32 -> global, bf16 -> Dlds [64][264] @65536
  unsigned short* ldsD = (unsigned short*)(lds + 65536);
  {
    float bv[2];
#pragma unroll
    for (int nj = 0; nj < 2; ++nj) bv[nj] = bd2[wid * 32 + nj * 16 + ln15];
#pragma unroll
    for (int mi = 0; mi < 4; ++mi) {
      int lrow = mi * 16 + kq * 4;
#pragma unroll
      for (int nj = 0; nj < 2; ++nj) {
        int col = wid * 32 + nj * 16 + ln15;
#pragma unroll
        for (int r = 0; r < 4; ++r) {
          float v = acc5[mi][nj][r] + bv[nj];
          v = v > 0.f ? v : 0.f;
          Df[(size_t)(bm + lrow + r) * 256 + col] = v;
          ldsD[(lrow + r) * 264 + col] = f2bf_bits(v);
        }
      }
    }
  }
  asm volatile("s_waitcnt lgkmcnt(0)");
  BAR(); MEMFENCE();

  // ---------------- head: out = sigmoid(widesum + dot(D, Wh[dom]) + bh) ----
  const int hrow = tid >> 3;           // 0..63
  const int he   = tid & 7;            // eighth of the 256-dim
  float s = 0.f;
  {
    const f32x4* wp = (const f32x4*)(wide + (size_t)(bm + hrow) * 256 + he * 32);
#pragma unroll
    for (int j = 0; j < 8; ++j) {
      f32x4 w = wp[j];
      s += w[0] + w[1] + w[2] + w[3];
    }
  }
  const int dm = dom[bm + hrow];
  {
    const f32x4* hp = (const f32x4*)(Wh + (size_t)dm * 256 + he * 32);
    const short8* dp = (const short8*)(ldsD + hrow * 264 + he * 32);
#pragma unroll
    for (int j = 0; j < 4; ++j) {
      short8 d8 = dp[j];
      f32x4 h0 = hp[2 * j], h1 = hp[2 * j + 1];
      s += bf_bits2f((unsigned short)d8[0]) * h0[0] +
           bf_bits2f((unsigned short)d8[1]) * h0[1] +
           bf_bits2f((unsigned short)d8[2]) * h0[2] +
           bf_bits2f((unsigned short)d8[3]) * h0[3] +
           bf_bits2f((unsigned short)d8[4]) * h1[0] +
           bf_bits2f((unsigned short)d8[5]) * h1[1] +
           bf_bits2f((unsigned short)d8[6]) * h1[2] +
           bf_bits2f((unsigned short)d8[7]) * h1[3];
    }
  }
  float* ldsH = (float*)(lds + 100352);
  ldsH[hrow * 8 + he] = s;
  asm volatile("s_waitcnt lgkmcnt(0)");
  BAR(); MEMFENCE();

  if (tid < 64) {
    float v = 0.f;
#pragma unroll
    for (int j = 0; j < 8; ++j) v += ldsH[tid * 8 + j];
    int dmr = dom[bm + tid];
    float x = v + bh[dmr];
    outp[bm + tid] = 1.f / (1.f + __expf(-x));
  }
}

// ---------------------------------------------------------------------------
extern "C" void kernel_launch(void* const* d_in, const int* in_sizes, int n_in,
                              void* d_out, int out_size, void* d_ws, size_t ws_size,
                              hipStream_t stream) {
  const float* wide = (const float*)d_in[0];
  const float* deep = (const float*)d_in[1];
  const int*   dom  = (const int*)d_in[2];
  const float* W1  = (const float*)d_in[3];
  const float* b1  = (const float*)d_in[4];
  const float* W2  = (const float*)d_in[5];
  const float* b2  = (const float*)d_in[6];
  const float* W3  = (const float*)d_in[7];
  const float* b3  = (const float*)d_in[8];
  const float* Wd1 = (const float*)d_in[9];
  const float* bd1 = (const float*)d_in[10];
  const float* Wd2 = (const float*)d_in[11];
  const float* bd2 = (const float*)d_in[12];
  const float* Wh  = (const float*)d_in[13];
  const float* bh  = (const float*)d_in[14];
  float* out = (float*)d_out;

  const int B = 16384;
  char* ws = (char*)d_ws;
  __hip_bfloat16* buf0 = (__hip_bfloat16*)ws;
  __hip_bfloat16* buf1 = (__hip_bfloat16*)(ws + 33554432ull);
  __hip_bfloat16* W1t  = (__hip_bfloat16*)(ws + 100663296ull);
  __hip_bfloat16* W2t  = W1t + 2048 * 1024;
  __hip_bfloat16* W3t  = W2t + 1024 * 2048;
  __hip_bfloat16* Wd1t = W3t + 512 * 1024;
  __hip_bfloat16* Wd2t = Wd1t + 512 * 512;

  prep<<<dim3(8192 + 1248), 256, 0, stream>>>(
      deep, (unsigned short*)buf0, W1, W1t, W2, W2t, W3, W3t, Wd1, Wd1t, Wd2, Wd2t);

  float* shared_out = out + B;
  float* d_out_f    = out + B + (size_t)B * 512;

  // L1: [B,1024]x[1024,2048] -> H1 (buf1)
  gemm_2c<<<dim3((2048 / 256) * (B / 256)), 512, 0, stream>>>(
      buf0, W1t, b1, buf1, nullptr, 2048, 1024, 2048 / 256);
  // L2: [B,2048]x[2048,1024] -> H2 (buf0)
  gemm_2c<<<dim3((1024 / 256) * (B / 256)), 512, 0, stream>>>(
      buf1, W2t, b2, buf0, nullptr, 1024, 2048, 1024 / 256);
  // L3+L4+L5+head fused: 64 rows/block
  tower<<<dim3(256), 512, 0, stream>>>(
      buf0, W3t, b3, Wd1t, bd1, Wd2t, bd2,
      shared_out, d_out_f, wide, dom, Wh, bh, out);
}